// Round 1
// baseline (19000.053 us; speedup 1.0000x reference)
//
#include <hip/hip_runtime.h>
#include <hip/hip_bf16.h>
#include <math.h>

#define BATCH 4
#define T 1024
#define D 768
#define L 8
#define H 12
#define F 3072
#define V 32000
#define DH 64
#define M (BATCH*T)   // 4096
#define D3 (3*D)      // 2304
#define SCALE 0.125f
#define QROWS 4

// ---- block-wide reduce (exactly 256 threads / 4 waves) ----
__device__ inline float block_reduce(float v, bool is_max, float* buf4) {
  int lane = threadIdx.x & 63, wid = threadIdx.x >> 6;
#pragma unroll
  for (int off = 32; off; off >>= 1) {
    float o = __shfl_down(v, off, 64);
    v = is_max ? fmaxf(v, o) : v + o;
  }
  if (lane == 0) buf4[wid] = v;
  __syncthreads();
  float r = is_max ? fmaxf(fmaxf(buf4[0], buf4[1]), fmaxf(buf4[2], buf4[3]))
                   : buf4[0] + buf4[1] + buf4[2] + buf4[3];
  __syncthreads();
  return r;
}

// ---- x = tok_emb[idx] + pos_emb ----
__global__ __launch_bounds__(256) void k_embed(const int* __restrict__ idx,
                                               const float* __restrict__ tok,
                                               const float* __restrict__ pos,
                                               float* __restrict__ x) {
  int i = blockIdx.x * 256 + threadIdx.x;   // grid covers M*D exactly
  int row = i / D, d = i - row * D;
  int t = row & (T - 1);
  x[i] = tok[(size_t)idx[row] * D + d] + pos[(size_t)t * D + d];
}

// ---- LayerNorm: one block per row of 768 ----
__global__ __launch_bounds__(256) void k_lnorm(const float* __restrict__ x,
                                               const float* __restrict__ w,
                                               const float* __restrict__ b,
                                               float* __restrict__ out) {
  __shared__ float buf4[4];
  int row = blockIdx.x, tid = threadIdx.x;
  const float* xr = x + (size_t)row * D;
  float v0 = xr[tid], v1 = xr[tid + 256], v2 = xr[tid + 512];
  float s = v0 + v1 + v2;
  float ss = v0 * v0 + v1 * v1 + v2 * v2;
  s = block_reduce(s, false, buf4);
  ss = block_reduce(ss, false, buf4);
  float mu = s * (1.0f / D);
  float var = ss * (1.0f / D) - mu * mu;
  float rs = rsqrtf(var + 1e-5f);
  float* orow = out + (size_t)row * D;
  orow[tid]       = (v0 - mu) * rs * w[tid]       + b[tid];
  orow[tid + 256] = (v1 - mu) * rs * w[tid + 256] + b[tid + 256];
  orow[tid + 512] = (v2 - mu) * rs * w[tid + 512] + b[tid + 512];
}

// ---- C[M,N] = A[M,K] @ W[N,K]^T (+bias +gelu +residual), f32 tiled ----
// flags: 1=bias, 2=residual add, 4=exact gelu
__global__ __launch_bounds__(256) void k_gemm_bt(
    const float* __restrict__ A, const float* __restrict__ W,
    const float* __restrict__ bias, const float* __restrict__ resid,
    float* __restrict__ C, int N, int K, int flags) {
  __shared__ float As[16][64];
  __shared__ float Bs[16][64];
  int tid = threadIdx.x;
  int bm = blockIdx.y, bn = blockIdx.x;
  int lrow = tid >> 2, lk4 = (tid & 3) << 2;
  int ty = tid >> 4, tx = tid & 15;
  const float* Ab = A + (size_t)bm * 64 * K;
  const float* Wb = W + (size_t)bn * 64 * K;
  float acc[4][4] = {{0.f}};
  for (int k0 = 0; k0 < K; k0 += 16) {
    float4 av = *(const float4*)(Ab + (size_t)lrow * K + k0 + lk4);
    float4 bv = *(const float4*)(Wb + (size_t)lrow * K + k0 + lk4);
    __syncthreads();
    As[lk4 + 0][lrow] = av.x; As[lk4 + 1][lrow] = av.y;
    As[lk4 + 2][lrow] = av.z; As[lk4 + 3][lrow] = av.w;
    Bs[lk4 + 0][lrow] = bv.x; Bs[lk4 + 1][lrow] = bv.y;
    Bs[lk4 + 2][lrow] = bv.z; Bs[lk4 + 3][lrow] = bv.w;
    __syncthreads();
#pragma unroll
    for (int k = 0; k < 16; ++k) {
      float4 a = *(const float4*)(&As[k][ty << 2]);
      float4 b = *(const float4*)(&Bs[k][tx << 2]);
      acc[0][0] += a.x * b.x; acc[0][1] += a.x * b.y; acc[0][2] += a.x * b.z; acc[0][3] += a.x * b.w;
      acc[1][0] += a.y * b.x; acc[1][1] += a.y * b.y; acc[1][2] += a.y * b.z; acc[1][3] += a.y * b.w;
      acc[2][0] += a.z * b.x; acc[2][1] += a.z * b.y; acc[2][2] += a.z * b.z; acc[2][3] += a.z * b.w;
      acc[3][0] += a.w * b.x; acc[3][1] += a.w * b.y; acc[3][2] += a.w * b.z; acc[3][3] += a.w * b.w;
    }
  }
  int m0 = bm * 64 + (ty << 2), n0 = bn * 64 + (tx << 2);
#pragma unroll
  for (int i = 0; i < 4; ++i) {
    size_t roff = (size_t)(m0 + i) * N + n0;
#pragma unroll
    for (int j = 0; j < 4; ++j) {
      float v = acc[i][j];
      if (flags & 1) v += bias[n0 + j];
      if (flags & 4) v = 0.5f * v * (1.0f + erff(v * 0.70710678118f));
      if (flags & 2) v += resid[roff + j];
      C[roff + j] = v;
    }
  }
}

// ---- causal attention: qkv[M,2304] -> y[M,768] ----
__global__ __launch_bounds__(256) void k_attn(const float* __restrict__ qkv,
                                              float* __restrict__ y) {
  __shared__ float qs[DH];
  __shared__ float s[T];
  __shared__ float red[4][DH];
  __shared__ float buf4[4];
  int tid = threadIdx.x;
  int bh = blockIdx.y;
  int b = bh / H, h = bh - b * H;
  int t0 = blockIdx.x * QROWS;
  int lane = tid & 63, wid = tid >> 6;
  const float* base = qkv + (size_t)b * T * D3;
  for (int r = 0; r < QROWS; ++r) {
    int t = t0 + r, klen = t + 1;
    if (tid < DH) qs[tid] = base[(size_t)t * D3 + h * DH + tid];
    __syncthreads();
    float lmax = -1e30f;
    for (int k = tid; k < klen; k += 256) {
      const float* Kr = base + (size_t)k * D3 + D + h * DH;
      float d = 0.f;
#pragma unroll
      for (int i = 0; i < 16; ++i) {
        float4 kv = *(const float4*)(Kr + (i << 2));
        float4 qv = *(const float4*)(qs + (i << 2));
        d += kv.x * qv.x + kv.y * qv.y + kv.z * qv.z + kv.w * qv.w;
      }
      d *= SCALE;
      s[k] = d;
      lmax = fmaxf(lmax, d);
    }
    float mx = block_reduce(lmax, true, buf4);
    float lsum = 0.f;
    for (int k = tid; k < klen; k += 256) {
      float p = __expf(s[k] - mx);
      s[k] = p;
      lsum += p;
    }
    float tot = block_reduce(lsum, false, buf4);
    __syncthreads();
    float acc = 0.f;
    const float* Vb = base + 2 * D + h * DH + lane;
#pragma unroll 4
    for (int k = wid; k < klen; k += 4)
      acc += s[k] * Vb[(size_t)k * D3];
    red[wid][lane] = acc;
    __syncthreads();
    if (wid == 0)
      y[(size_t)(b * T + t) * D + h * DH + lane] =
          (red[0][lane] + red[1][lane] + red[2][lane] + red[3][lane]) / tot;
    __syncthreads();
  }
}

// ---- per-row NLL from logits ----
__global__ __launch_bounds__(256) void k_loss_row(const float* __restrict__ logits,
                                                  const int* __restrict__ targets,
                                                  float* __restrict__ nll) {
  __shared__ float buf4[4];
  int row = blockIdx.x, tid = threadIdx.x;
  const float* lr = logits + (size_t)row * V;
  float m = -1e30f;
  for (int j = tid; j < V; j += 256) m = fmaxf(m, lr[j]);
  m = block_reduce(m, true, buf4);
  float sum = 0.f;
  for (int j = tid; j < V; j += 256) sum += __expf(lr[j] - m);
  sum = block_reduce(sum, false, buf4);
  if (tid == 0) {
    int tgt = targets[row];
    bool valid = (tgt != -100);
    nll[row] = valid ? (m + logf(sum) - lr[tgt]) : 0.f;
  }
}

__global__ __launch_bounds__(256) void k_loss_final(const float* __restrict__ nll,
                                                    const int* __restrict__ targets,
                                                    float* __restrict__ out) {
  __shared__ float buf4[4];
  float s = 0.f, c = 0.f;
  for (int i = threadIdx.x; i < M; i += 256) {
    s += nll[i];
    c += (targets[i] != -100) ? 1.f : 0.f;
  }
  s = block_reduce(s, false, buf4);
  c = block_reduce(c, false, buf4);
  if (threadIdx.x == 0) out[0] = s / fmaxf(c, 1.f);
}

extern "C" void kernel_launch(void* const* d_in, const int* in_sizes, int n_in,
                              void* d_out, int out_size, void* d_ws, size_t ws_size,
                              hipStream_t stream) {
  const int* idx       = (const int*)d_in[0];
  const int* targets   = (const int*)d_in[1];
  const float* tok     = (const float*)d_in[2];
  const float* pos     = (const float*)d_in[3];
  const float* qkv_w   = (const float*)d_in[4];
  const float* qkv_b   = (const float*)d_in[5];
  const float* proj_w  = (const float*)d_in[6];
  const float* proj_b  = (const float*)d_in[7];
  const float* fc1_w   = (const float*)d_in[8];
  const float* fc1_b   = (const float*)d_in[9];
  const float* fc2_w   = (const float*)d_in[10];
  const float* fc2_b   = (const float*)d_in[11];
  const float* ln1_w   = (const float*)d_in[12];
  const float* ln1_b   = (const float*)d_in[13];
  const float* ln2_w   = (const float*)d_in[14];
  const float* ln2_b   = (const float*)d_in[15];
  const float* lnf_w   = (const float*)d_in[16];
  const float* lnf_b   = (const float*)d_in[17];

  float* logits = (float*)d_out;
  // ws scratch: x, h, y, nll  (~38 MB)
  float* x   = (float*)d_ws;
  float* h   = x + (size_t)M * D;
  float* yb  = h + (size_t)M * D;
  float* nll = yb + (size_t)M * D;
  // big intermediates live inside the (524 MB) logits region; logits are
  // only produced after their last use, overwriting them is fine.
  float* qkvb = logits;                       // needs 9.44M floats
  float* f1   = logits + ((size_t)1 << 24);   // needs 12.6M floats @ offset 16.7M

  k_embed<<<(M * D) / 256, 256, 0, stream>>>(idx, tok, pos, x);

  for (int l = 0; l < L; ++l) {
    k_lnorm<<<M, 256, 0, stream>>>(x, ln1_w + (size_t)l * D, ln1_b + (size_t)l * D, h);
    k_gemm_bt<<<dim3(D3 / 64, M / 64), 256, 0, stream>>>(
        h, qkv_w + (size_t)l * D3 * D, qkv_b + (size_t)l * D3, nullptr, qkvb, D3, D, 1);
    k_attn<<<dim3(T / QROWS, BATCH * H), 256, 0, stream>>>(qkvb, yb);
    k_gemm_bt<<<dim3(D / 64, M / 64), 256, 0, stream>>>(
        yb, proj_w + (size_t)l * D * D, proj_b + (size_t)l * D, x, x, D, D, 3);
    k_lnorm<<<M, 256, 0, stream>>>(x, ln2_w + (size_t)l * D, ln2_b + (size_t)l * D, h);
    k_gemm_bt<<<dim3(F / 64, M / 64), 256, 0, stream>>>(
        h, fc1_w + (size_t)l * F * D, fc1_b + (size_t)l * F, nullptr, f1, F, D, 5);
    k_gemm_bt<<<dim3(D / 64, M / 64), 256, 0, stream>>>(
        f1, fc2_w + (size_t)l * D * F, fc2_b + (size_t)l * D, x, x, D, F, 3);
  }

  k_lnorm<<<M, 256, 0, stream>>>(x, lnf_w, lnf_b, h);
  k_gemm_bt<<<dim3(V / 64, M / 64), 256, 0, stream>>>(
      h, tok, nullptr, nullptr, logits, V, D, 0);
  k_loss_row<<<M, 256, 0, stream>>>(logits, targets, nll);
  k_loss_final<<<1, 256, 0, stream>>>(nll, targets, logits + (size_t)M * V);
}

// Round 2
// 11265.701 us; speedup vs baseline: 1.6865x; 1.6865x over previous
//
#include <hip/hip_runtime.h>
#include <hip/hip_bf16.h>
#include <math.h>

#define BATCH 4
#define T 1024
#define D 768
#define L 8
#define H 12
#define F 3072
#define V 32000
#define DH 64
#define M (BATCH*T)   // 4096
#define D3 (3*D)      // 2304
#define SCALE 0.125f
#define QROWS 4
#define VCHUNK 6400   // lm_head N-chunk (50 tiles of 128)

typedef unsigned short u16;
typedef __attribute__((ext_vector_type(8))) short bf16x8;
typedef __attribute__((ext_vector_type(4))) float f32x4;

__device__ inline u16 f2b(float f) {
  __hip_bfloat16 h = __float2bfloat16(f);
  return *(u16*)&h;
}

// async global->LDS, 16B per lane; LDS dest is wave-uniform base + lane*16
__device__ inline void gll16(const void* g, void* l) {
  __builtin_amdgcn_global_load_lds(
      (const __attribute__((address_space(1))) unsigned int*)g,
      (__attribute__((address_space(3))) unsigned int*)l, 16, 0, 0);
}

// ---- block-wide reduce (exactly 256 threads / 4 waves) ----
__device__ inline float block_reduce(float v, bool is_max, float* buf4) {
  int lane = threadIdx.x & 63, wid = threadIdx.x >> 6;
#pragma unroll
  for (int off = 32; off; off >>= 1) {
    float o = __shfl_down(v, off, 64);
    v = is_max ? fmaxf(v, o) : v + o;
  }
  if (lane == 0) buf4[wid] = v;
  __syncthreads();
  float r = is_max ? fmaxf(fmaxf(buf4[0], buf4[1]), fmaxf(buf4[2], buf4[3]))
                   : buf4[0] + buf4[1] + buf4[2] + buf4[3];
  __syncthreads();
  return r;
}

// ---- x = tok_emb[idx] + pos_emb ----
__global__ __launch_bounds__(256) void k_embed(const int* __restrict__ idx,
                                               const float* __restrict__ tok,
                                               const float* __restrict__ pos,
                                               float* __restrict__ x) {
  int i = blockIdx.x * 256 + threadIdx.x;
  int row = i / D, d = i - row * D;
  int t = row & (T - 1);
  x[i] = tok[(size_t)idx[row] * D + d] + pos[(size_t)t * D + d];
}

// ---- f32 -> bf16 convert, 4 elems/thread ----
__global__ __launch_bounds__(256) void k_cvt(const float* __restrict__ in,
                                             u16* __restrict__ out, int n4) {
  int i = blockIdx.x * 256 + threadIdx.x;
  if (i >= n4) return;
  float4 v = ((const float4*)in)[i];
  ushort4 o;
  o.x = f2b(v.x); o.y = f2b(v.y); o.z = f2b(v.z); o.w = f2b(v.w);
  ((ushort4*)out)[i] = o;
}

// ---- LayerNorm: one block per row of 768, bf16 out ----
__global__ __launch_bounds__(256) void k_lnorm(const float* __restrict__ x,
                                               const float* __restrict__ w,
                                               const float* __restrict__ b,
                                               u16* __restrict__ out) {
  __shared__ float buf4[4];
  int row = blockIdx.x, tid = threadIdx.x;
  const float* xr = x + (size_t)row * D;
  float v0 = xr[tid], v1 = xr[tid + 256], v2 = xr[tid + 512];
  float s = v0 + v1 + v2;
  float ss = v0 * v0 + v1 * v1 + v2 * v2;
  s = block_reduce(s, false, buf4);
  ss = block_reduce(ss, false, buf4);
  float mu = s * (1.0f / D);
  float var = ss * (1.0f / D) - mu * mu;
  float rs = rsqrtf(var + 1e-5f);
  u16* orow = out + (size_t)row * D;
  orow[tid]       = f2b((v0 - mu) * rs * w[tid]       + b[tid]);
  orow[tid + 256] = f2b((v1 - mu) * rs * w[tid + 256] + b[tid + 256]);
  orow[tid + 512] = f2b((v2 - mu) * rs * w[tid + 512] + b[tid + 512]);
}

// ---- MFMA GEMM: C[M,N] = A[M,K] @ W[N,K]^T, bf16 in, f32 acc ----
// m97 structure: 128x128 tile, BK=32, 4 waves, global_load_lds(16B)
// flags: 1=bias, 2=residual add (f32), 4=exact gelu, 8=bf16 output
__global__ __launch_bounds__(256) void k_mfma_gemm(
    const u16* __restrict__ A, const u16* __restrict__ W,
    const float* __restrict__ bias, const float* __restrict__ resid,
    void* __restrict__ Cout, int K, int ldC, int flags) {
  __shared__ __attribute__((aligned(16))) u16 lA[128 * 32];
  __shared__ __attribute__((aligned(16))) u16 lB[128 * 32];
  int tid = threadIdx.x;
  int w = tid >> 6, lane = tid & 63;
  int bn = blockIdx.x, bm = blockIdx.y;
  const u16* Ab = A + (size_t)bm * 128 * K;
  const u16* Wb = W + (size_t)bn * 128 * K;
  // staging: wave w fills chunks w and w+4 (16 rows x 32 cols each)
  int r0 = w * 16 + (lane >> 2);
  int r1 = 64 + r0;
  int kc = (lane & 3) * 8;
  // fragment coords (16x16x32): row/col = lane&15, k0 = (lane>>4)*8
  int wr = (w >> 1) * 64, wc = (w & 1) * 64;
  int frow = lane & 15, fk = (lane >> 4) * 8;
  f32x4 acc[4][4];
#pragma unroll
  for (int i = 0; i < 4; ++i)
#pragma unroll
    for (int j = 0; j < 4; ++j) acc[i][j] = (f32x4)(0.f);

  for (int k0 = 0; k0 < K; k0 += 32) {
    __syncthreads();  // previous iteration's LDS reads complete
    gll16(Ab + (size_t)r0 * K + k0 + kc, lA + w * 512);
    gll16(Ab + (size_t)r1 * K + k0 + kc, lA + (w + 4) * 512);
    gll16(Wb + (size_t)r0 * K + k0 + kc, lB + w * 512);
    gll16(Wb + (size_t)r1 * K + k0 + kc, lB + (w + 4) * 512);
    __syncthreads();  // compiler drains vmcnt(0) before s_barrier
    bf16x8 af[4], bfr[4];
#pragma unroll
    for (int i = 0; i < 4; ++i)
      af[i] = *(const bf16x8*)(lA + (wr + i * 16 + frow) * 32 + fk);
#pragma unroll
    for (int j = 0; j < 4; ++j)
      bfr[j] = *(const bf16x8*)(lB + (wc + j * 16 + frow) * 32 + fk);
#pragma unroll
    for (int i = 0; i < 4; ++i)
#pragma unroll
      for (int j = 0; j < 4; ++j)
        acc[i][j] = __builtin_amdgcn_mfma_f32_16x16x32_bf16(af[i], bfr[j], acc[i][j], 0, 0, 0);
  }

  // C/D layout: col = lane&15, row = (lane>>4)*4 + q
  int m0 = bm * 128 + wr + (lane >> 4) * 4;
  int n0 = bn * 128 + wc + (lane & 15);
#pragma unroll
  for (int i = 0; i < 4; ++i) {
#pragma unroll
    for (int j = 0; j < 4; ++j) {
      int n = n0 + j * 16;
      float bv = (flags & 1) ? bias[n] : 0.f;
#pragma unroll
      for (int q = 0; q < 4; ++q) {
        int m = m0 + i * 16 + q;
        size_t off = (size_t)m * ldC + n;
        float v = acc[i][j][q] + bv;
        if (flags & 4) v = 0.5f * v * (1.0f + erff(v * 0.70710678118f));
        if (flags & 2) v += resid[off];
        if (flags & 8) ((u16*)Cout)[off] = f2b(v);
        else           ((float*)Cout)[off] = v;
      }
    }
  }
}

// ---- causal attention: qkv[M,2304] f32 -> y[M,768] bf16 ----
__global__ __launch_bounds__(256) void k_attn(const float* __restrict__ qkv,
                                              u16* __restrict__ y) {
  __shared__ float qs[DH];
  __shared__ float s[T];
  __shared__ float red[4][DH];
  __shared__ float buf4[4];
  int tid = threadIdx.x;
  int bh = blockIdx.y;
  int b = bh / H, h = bh - b * H;
  int t0 = blockIdx.x * QROWS;
  int lane = tid & 63, wid = tid >> 6;
  const float* base = qkv + (size_t)b * T * D3;
  for (int r = 0; r < QROWS; ++r) {
    int t = t0 + r, klen = t + 1;
    if (tid < DH) qs[tid] = base[(size_t)t * D3 + h * DH + tid];
    __syncthreads();
    float lmax = -1e30f;
    for (int k = tid; k < klen; k += 256) {
      const float* Kr = base + (size_t)k * D3 + D + h * DH;
      float d = 0.f;
#pragma unroll
      for (int i = 0; i < 16; ++i) {
        float4 kv = *(const float4*)(Kr + (i << 2));
        float4 qv = *(const float4*)(qs + (i << 2));
        d += kv.x * qv.x + kv.y * qv.y + kv.z * qv.z + kv.w * qv.w;
      }
      d *= SCALE;
      s[k] = d;
      lmax = fmaxf(lmax, d);
    }
    float mx = block_reduce(lmax, true, buf4);
    float lsum = 0.f;
    for (int k = tid; k < klen; k += 256) {
      float p = __expf(s[k] - mx);
      s[k] = p;
      lsum += p;
    }
    float tot = block_reduce(lsum, false, buf4);
    __syncthreads();
    float acc = 0.f;
    const float* Vb = base + 2 * D + h * DH + lane;
#pragma unroll 4
    for (int k = wid; k < klen; k += 4)
      acc += s[k] * Vb[(size_t)k * D3];
    red[wid][lane] = acc;
    __syncthreads();
    if (wid == 0)
      y[(size_t)(b * T + t) * D + h * DH + lane] =
          f2b((red[0][lane] + red[1][lane] + red[2][lane] + red[3][lane]) / tot);
    __syncthreads();
  }
}

// ---- per-row NLL from logits ----
__global__ __launch_bounds__(256) void k_loss_row(const float* __restrict__ logits,
                                                  const int* __restrict__ targets,
                                                  float* __restrict__ nll) {
  __shared__ float buf4[4];
  int row = blockIdx.x, tid = threadIdx.x;
  const float* lr = logits + (size_t)row * V;
  float m = -1e30f;
  for (int j = tid; j < V; j += 256) m = fmaxf(m, lr[j]);
  m = block_reduce(m, true, buf4);
  float sum = 0.f;
  for (int j = tid; j < V; j += 256) sum += __expf(lr[j] - m);
  sum = block_reduce(sum, false, buf4);
  if (tid == 0) {
    int tgt = targets[row];
    bool valid = (tgt != -100);
    nll[row] = valid ? (m + logf(sum) - lr[tgt]) : 0.f;
  }
}

__global__ __launch_bounds__(256) void k_loss_final(const float* __restrict__ nll,
                                                    const int* __restrict__ targets,
                                                    float* __restrict__ out) {
  __shared__ float buf4[4];
  float s = 0.f, c = 0.f;
  for (int i = threadIdx.x; i < M; i += 256) {
    s += nll[i];
    c += (targets[i] != -100) ? 1.f : 0.f;
  }
  s = block_reduce(s, false, buf4);
  c = block_reduce(c, false, buf4);
  if (threadIdx.x == 0) out[0] = s / fmaxf(c, 1.f);
}

extern "C" void kernel_launch(void* const* d_in, const int* in_sizes, int n_in,
                              void* d_out, int out_size, void* d_ws, size_t ws_size,
                              hipStream_t stream) {
  const int* idx       = (const int*)d_in[0];
  const int* targets   = (const int*)d_in[1];
  const float* tok     = (const float*)d_in[2];
  const float* pos     = (const float*)d_in[3];
  const float* qkv_w   = (const float*)d_in[4];
  const float* qkv_b   = (const float*)d_in[5];
  const float* proj_w  = (const float*)d_in[6];
  const float* proj_b  = (const float*)d_in[7];
  const float* fc1_w   = (const float*)d_in[8];
  const float* fc1_b   = (const float*)d_in[9];
  const float* fc2_w   = (const float*)d_in[10];
  const float* fc2_b   = (const float*)d_in[11];
  const float* ln1_w   = (const float*)d_in[12];
  const float* ln1_b   = (const float*)d_in[13];
  const float* ln2_w   = (const float*)d_in[14];
  const float* ln2_b   = (const float*)d_in[15];
  const float* lnf_w   = (const float*)d_in[16];
  const float* lnf_b   = (const float*)d_in[17];

  float* logits = (float*)d_out;

  // ---- ws layout (~35 MB) ----
  char* ws = (char*)d_ws;
  float* x  = (float*)ws;                   // M*D f32      12.58 MB
  u16* hb   = (u16*)(ws + 12582912);        // M*D bf16      6.29 MB
  u16* yb   = (u16*)(ws + 18874368);        // M*D bf16      6.29 MB
  u16* wb   = (u16*)(ws + 25165824);        // VCHUNK*D bf16 9.83 MB
  float* nll = (float*)(ws + 34996224);     // M f32        16 KB

  // ---- d_out scratch (dead before logits are written) ----
  float* qkvb = logits;                              // M*D3 f32   37.75 MB
  u16* f1b    = (u16*)(logits + 9437184);            // M*F bf16   25.17 MB
  u16* wqkv   = (u16*)(logits + 15728640);           // L*D3*D bf16
  u16* wproj  = (u16*)(logits + 22806528);           // L*D*D
  u16* wfc1   = (u16*)(logits + 25165824);           // L*F*D
  u16* wfc2   = (u16*)(logits + 34603008);           // L*D*F

  // convert all block weights to bf16 once per call
  k_cvt<<<(L * D3 * D / 4 + 255) / 256, 256, 0, stream>>>(qkv_w, wqkv, L * D3 * D / 4);
  k_cvt<<<(L * D * D / 4 + 255) / 256, 256, 0, stream>>>(proj_w, wproj, L * D * D / 4);
  k_cvt<<<(L * F * D / 4 + 255) / 256, 256, 0, stream>>>(fc1_w, wfc1, L * F * D / 4);
  k_cvt<<<(L * D * F / 4 + 255) / 256, 256, 0, stream>>>(fc2_w, wfc2, L * D * F / 4);

  k_embed<<<(M * D) / 256, 256, 0, stream>>>(idx, tok, pos, x);

  for (int l = 0; l < L; ++l) {
    k_lnorm<<<M, 256, 0, stream>>>(x, ln1_w + (size_t)l * D, ln1_b + (size_t)l * D, hb);
    k_mfma_gemm<<<dim3(D3 / 128, M / 128), 256, 0, stream>>>(
        hb, wqkv + (size_t)l * D3 * D, qkv_b + (size_t)l * D3, nullptr, qkvb, D, D3, 1);
    k_attn<<<dim3(T / QROWS, BATCH * H), 256, 0, stream>>>(qkvb, yb);
    k_mfma_gemm<<<dim3(D / 128, M / 128), 256, 0, stream>>>(
        yb, wproj + (size_t)l * D * D, proj_b + (size_t)l * D, x, x, D, D, 3);
    k_lnorm<<<M, 256, 0, stream>>>(x, ln2_w + (size_t)l * D, ln2_b + (size_t)l * D, hb);
    k_mfma_gemm<<<dim3(F / 128, M / 128), 256, 0, stream>>>(
        hb, wfc1 + (size_t)l * F * D, fc1_b + (size_t)l * F, nullptr, f1b, D, F, 13);
    k_mfma_gemm<<<dim3(D / 128, M / 128), 256, 0, stream>>>(
        f1b, wfc2 + (size_t)l * D * F, fc2_b + (size_t)l * D, x, x, F, D, 3);
  }

  k_lnorm<<<M, 256, 0, stream>>>(x, lnf_w, lnf_b, hb);
  // tied lm_head in 5 N-chunks; tok converted chunk-wise into ws
  for (int c = 0; c < 5; ++c) {
    k_cvt<<<(VCHUNK * D / 4 + 255) / 256, 256, 0, stream>>>(
        tok + (size_t)c * VCHUNK * D, wb, VCHUNK * D / 4);
    k_mfma_gemm<<<dim3(VCHUNK / 128, M / 128), 256, 0, stream>>>(
        hb, wb, nullptr, nullptr, logits + (size_t)c * VCHUNK, D, V, 0);
  }
  k_loss_row<<<M, 256, 0, stream>>>(logits, targets, nll);
  k_loss_final<<<1, 256, 0, stream>>>(nll, targets, logits + (size_t)M * V);
}

// Round 3
// 2985.255 us; speedup vs baseline: 6.3646x; 3.7738x over previous
//
#include <hip/hip_runtime.h>
#include <hip/hip_bf16.h>
#include <math.h>

#define BATCH 4
#define T 1024
#define D 768
#define L 8
#define H 12
#define F 3072
#define V 32000
#define DH 64
#define M (BATCH*T)   // 4096
#define D3 (3*D)      // 2304
#define SCALE 0.125f
#define VCHUNK 6400   // lm_head N-chunk (50 tiles of 128)

typedef unsigned short u16;
typedef __attribute__((ext_vector_type(8))) short bf16x8;
typedef __attribute__((ext_vector_type(4))) float f32x4;

__device__ inline u16 f2b(float f) {
  __hip_bfloat16 h = __float2bfloat16(f);
  return *(u16*)&h;
}

// async global->LDS, 16B per lane; LDS dest is wave-uniform base + lane*16
__device__ inline void gll16(const void* g, void* l) {
  __builtin_amdgcn_global_load_lds(
      (const __attribute__((address_space(1))) unsigned int*)g,
      (__attribute__((address_space(3))) unsigned int*)l, 16, 0, 0);
}

// XOR swizzle for [64][64] u16 LDS tiles: spreads row-stride-128B across banks.
// Bijective within each row's 64 elems (XOR touches elem bits 3..5 only), so
// 8-elem (16B) aligned groups stay contiguous.
__device__ inline int swzi(int r, int c) {
  return (r * 64 + c) ^ ((((r & 7) ^ ((r >> 3) & 7))) << 3);
}

// ---- block-wide reduce (exactly 256 threads / 4 waves) ----
__device__ inline float block_reduce(float v, bool is_max, float* buf4) {
  int lane = threadIdx.x & 63, wid = threadIdx.x >> 6;
#pragma unroll
  for (int off = 32; off; off >>= 1) {
    float o = __shfl_down(v, off, 64);
    v = is_max ? fmaxf(v, o) : v + o;
  }
  if (lane == 0) buf4[wid] = v;
  __syncthreads();
  float r = is_max ? fmaxf(fmaxf(buf4[0], buf4[1]), fmaxf(buf4[2], buf4[3]))
                   : buf4[0] + buf4[1] + buf4[2] + buf4[3];
  __syncthreads();
  return r;
}

// ---- x = tok_emb[idx] + pos_emb ----
__global__ __launch_bounds__(256) void k_embed(const int* __restrict__ idx,
                                               const float* __restrict__ tok,
                                               const float* __restrict__ pos,
                                               float* __restrict__ x) {
  int i = blockIdx.x * 256 + threadIdx.x;
  int row = i / D, d = i - row * D;
  int t = row & (T - 1);
  x[i] = tok[(size_t)idx[row] * D + d] + pos[(size_t)t * D + d];
}

// ---- f32 -> bf16 convert, 4 elems/thread ----
__global__ __launch_bounds__(256) void k_cvt(const float* __restrict__ in,
                                             u16* __restrict__ out, int n4) {
  int i = blockIdx.x * 256 + threadIdx.x;
  if (i >= n4) return;
  float4 v = ((const float4*)in)[i];
  ushort4 o;
  o.x = f2b(v.x); o.y = f2b(v.y); o.z = f2b(v.z); o.w = f2b(v.w);
  ((ushort4*)out)[i] = o;
}

// ---- LayerNorm: one block per row of 768, bf16 out ----
__global__ __launch_bounds__(256) void k_lnorm(const float* __restrict__ x,
                                               const float* __restrict__ w,
                                               const float* __restrict__ b,
                                               u16* __restrict__ out) {
  __shared__ float buf4[4];
  int row = blockIdx.x, tid = threadIdx.x;
  const float* xr = x + (size_t)row * D;
  float v0 = xr[tid], v1 = xr[tid + 256], v2 = xr[tid + 512];
  float s = v0 + v1 + v2;
  float ss = v0 * v0 + v1 * v1 + v2 * v2;
  s = block_reduce(s, false, buf4);
  ss = block_reduce(ss, false, buf4);
  float mu = s * (1.0f / D);
  float var = ss * (1.0f / D) - mu * mu;
  float rs = rsqrtf(var + 1e-5f);
  u16* orow = out + (size_t)row * D;
  orow[tid]       = f2b((v0 - mu) * rs * w[tid]       + b[tid]);
  orow[tid + 256] = f2b((v1 - mu) * rs * w[tid + 256] + b[tid + 256]);
  orow[tid + 512] = f2b((v2 - mu) * rs * w[tid + 512] + b[tid + 512]);
}

// ---- MFMA GEMM: C[M,N] = A[M,K] @ W[N,K]^T, bf16 in, f32 acc ----
// flags: 1=bias, 2=residual add (f32), 4=exact gelu, 8=bf16 output
__global__ __launch_bounds__(256) void k_mfma_gemm(
    const u16* __restrict__ A, const u16* __restrict__ W,
    const float* __restrict__ bias, const float* __restrict__ resid,
    void* __restrict__ Cout, int K, int ldC, int flags) {
  __shared__ __attribute__((aligned(16))) u16 lA[128 * 32];
  __shared__ __attribute__((aligned(16))) u16 lB[128 * 32];
  int tid = threadIdx.x;
  int w = tid >> 6, lane = tid & 63;
  int bn = blockIdx.x, bm = blockIdx.y;
  const u16* Ab = A + (size_t)bm * 128 * K;
  const u16* Wb = W + (size_t)bn * 128 * K;
  int r0 = w * 16 + (lane >> 2);
  int r1 = 64 + r0;
  int kc = (lane & 3) * 8;
  int wr = (w >> 1) * 64, wc = (w & 1) * 64;
  int frow = lane & 15, fk = (lane >> 4) * 8;
  f32x4 acc[4][4];
#pragma unroll
  for (int i = 0; i < 4; ++i)
#pragma unroll
    for (int j = 0; j < 4; ++j) acc[i][j] = (f32x4)(0.f);

  for (int k0 = 0; k0 < K; k0 += 32) {
    __syncthreads();
    gll16(Ab + (size_t)r0 * K + k0 + kc, lA + w * 512);
    gll16(Ab + (size_t)r1 * K + k0 + kc, lA + (w + 4) * 512);
    gll16(Wb + (size_t)r0 * K + k0 + kc, lB + w * 512);
    gll16(Wb + (size_t)r1 * K + k0 + kc, lB + (w + 4) * 512);
    __syncthreads();
    bf16x8 af[4], bfr[4];
#pragma unroll
    for (int i = 0; i < 4; ++i)
      af[i] = *(const bf16x8*)(lA + (wr + i * 16 + frow) * 32 + fk);
#pragma unroll
    for (int j = 0; j < 4; ++j)
      bfr[j] = *(const bf16x8*)(lB + (wc + j * 16 + frow) * 32 + fk);
#pragma unroll
    for (int i = 0; i < 4; ++i)
#pragma unroll
      for (int j = 0; j < 4; ++j)
        acc[i][j] = __builtin_amdgcn_mfma_f32_16x16x32_bf16(af[i], bfr[j], acc[i][j], 0, 0, 0);
  }

  int m0 = bm * 128 + wr + (lane >> 4) * 4;
  int n0 = bn * 128 + wc + (lane & 15);
#pragma unroll
  for (int i = 0; i < 4; ++i) {
#pragma unroll
    for (int j = 0; j < 4; ++j) {
      int n = n0 + j * 16;
      float bv = (flags & 1) ? bias[n] : 0.f;
#pragma unroll
      for (int q = 0; q < 4; ++q) {
        int m = m0 + i * 16 + q;
        size_t off = (size_t)m * ldC + n;
        float v = acc[i][j][q] + bv;
        if (flags & 4) v = 0.5f * v * (1.0f + erff(v * 0.70710678118f));
        if (flags & 2) v += resid[off];
        if (flags & 8) ((u16*)Cout)[off] = f2b(v);
        else           ((float*)Cout)[off] = v;
      }
    }
  }
}

// ---- MFMA flash attention: qkv bf16 [M,2304] -> y bf16 [M,768] ----
// block = (q-tile of 64 rows) x (b,h); 4 waves, wave w owns q-rows [w*16,w*16+16)
__global__ __launch_bounds__(256) void k_fattn(const u16* __restrict__ qkv,
                                               u16* __restrict__ y) {
  __shared__ __attribute__((aligned(16))) u16 lQ[64 * 64];
  __shared__ __attribute__((aligned(16))) u16 lK[64 * 64];
  __shared__ __attribute__((aligned(16))) u16 lVt[64 * 64];  // swizzled, Vt[d][k]
  __shared__ __attribute__((aligned(16))) u16 lP[64 * 64];   // swizzled, P[q][k]
  int tid = threadIdx.x;
  int w = tid >> 6, lane = tid & 63;
  int qt = blockIdx.x;
  int bh = blockIdx.y, b = bh / H, h = bh - b * H;
  int q0 = qt * 64;
  const u16* base = qkv + (size_t)b * T * D3 + h * DH;
  int srow = lane >> 3;            // 0..7
  int scol = (lane & 7) * 8;       // 0..56
  int frow = lane & 15, fk = (lane >> 4) * 8;
  int w16 = w * 16;
  int qrow = (lane >> 4) * 4;      // + qi = local q row within strip

  // stage Q tile (rows q0..q0+63)
  gll16(base + (size_t)(q0 + w * 8 + srow) * D3 + scol, lQ + (w * 8) * 64);
  gll16(base + (size_t)(q0 + 32 + w * 8 + srow) * D3 + scol, lQ + (32 + w * 8) * 64);

  float m_r[4] = {-1e30f, -1e30f, -1e30f, -1e30f};
  float l_r[4] = {0.f, 0.f, 0.f, 0.f};
  f32x4 o[4];
#pragma unroll
  for (int i = 0; i < 4; ++i) o[i] = (f32x4)(0.f);

  for (int kt = 0; kt <= qt; ++kt) {
    __syncthreads();  // iter0: barrier syncs Q staging; else: prev-iter LDS reads done
    int k0 = kt * 64;
    // stage K tile
    gll16(base + D + (size_t)(k0 + w * 8 + srow) * D3 + scol, lK + (w * 8) * 64);
    gll16(base + D + (size_t)(k0 + 32 + w * 8 + srow) * D3 + scol, lK + (32 + w * 8) * 64);
    // stage V transposed (reg transpose, swizzled writes)
#pragma unroll
    for (int p = 0; p < 2; ++p) {
      int kk = p * 32 + w * 8 + srow;
      uint4 vv = *(const uint4*)(base + 2 * D + (size_t)(k0 + kk) * D3 + scol);
      unsigned vals[4] = {vv.x, vv.y, vv.z, vv.w};
#pragma unroll
      for (int e = 0; e < 4; ++e) {
        lVt[swzi(scol + 2 * e, kk)]     = (u16)(vals[e] & 0xffff);
        lVt[swzi(scol + 2 * e + 1, kk)] = (u16)(vals[e] >> 16);
      }
    }
    __syncthreads();

    // S = Q K^T for this wave's 16-row strip (16 x 64)
    bf16x8 aq0 = *(const bf16x8*)(lQ + (w16 + frow) * 64 + fk);
    bf16x8 aq1 = *(const bf16x8*)(lQ + (w16 + frow) * 64 + 32 + fk);
    f32x4 sv[4];
#pragma unroll
    for (int kn = 0; kn < 4; ++kn) {
      bf16x8 bk0 = *(const bf16x8*)(lK + (kn * 16 + frow) * 64 + fk);
      bf16x8 bk1 = *(const bf16x8*)(lK + (kn * 16 + frow) * 64 + 32 + fk);
      sv[kn] = __builtin_amdgcn_mfma_f32_16x16x32_bf16(aq0, bk0, (f32x4)(0.f), 0, 0, 0);
      sv[kn] = __builtin_amdgcn_mfma_f32_16x16x32_bf16(aq1, bk1, sv[kn], 0, 0, 0);
    }
    // scale + causal mask (only diagonal tile needs masking)
#pragma unroll
    for (int kn = 0; kn < 4; ++kn) {
#pragma unroll
      for (int qi = 0; qi < 4; ++qi) {
        float v = sv[kn][qi] * SCALE;
        if (kt == qt) {
          int qg = q0 + w16 + qrow + qi;
          int kg = k0 + kn * 16 + frow;
          if (kg > qg) v = -1e30f;
        }
        sv[kn][qi] = v;
      }
    }
    // online softmax (row spread across 16-lane group x 4 kn frags)
    float alpha[4];
#pragma unroll
    for (int qi = 0; qi < 4; ++qi) {
      float rm = fmaxf(fmaxf(sv[0][qi], sv[1][qi]), fmaxf(sv[2][qi], sv[3][qi]));
      rm = fmaxf(rm, __shfl_xor(rm, 1, 64));
      rm = fmaxf(rm, __shfl_xor(rm, 2, 64));
      rm = fmaxf(rm, __shfl_xor(rm, 4, 64));
      rm = fmaxf(rm, __shfl_xor(rm, 8, 64));
      float mn = fmaxf(m_r[qi], rm);
      alpha[qi] = __expf(m_r[qi] - mn);
      m_r[qi] = mn;
      float rs = 0.f;
#pragma unroll
      for (int kn = 0; kn < 4; ++kn) {
        float p = __expf(sv[kn][qi] - mn);
        sv[kn][qi] = p;
        rs += p;
      }
      rs += __shfl_xor(rs, 1, 64);
      rs += __shfl_xor(rs, 2, 64);
      rs += __shfl_xor(rs, 4, 64);
      rs += __shfl_xor(rs, 8, 64);
      l_r[qi] = l_r[qi] * alpha[qi] + rs;
#pragma unroll
      for (int df = 0; df < 4; ++df) o[df][qi] *= alpha[qi];
    }
    // write P (bf16) to this wave's private LDS strip (swizzled)
#pragma unroll
    for (int kn = 0; kn < 4; ++kn)
#pragma unroll
      for (int qi = 0; qi < 4; ++qi)
        lP[swzi(w16 + qrow + qi, kn * 16 + frow)] = f2b(sv[kn][qi]);
    // P.Vt MFMA (same-wave LDS RAW: DS pipe is in-order per wave)
    bf16x8 pa0 = *(const bf16x8*)(lP + swzi(w16 + frow, fk));
    bf16x8 pa1 = *(const bf16x8*)(lP + swzi(w16 + frow, 32 + fk));
#pragma unroll
    for (int df = 0; df < 4; ++df) {
      bf16x8 bv0 = *(const bf16x8*)(lVt + swzi(df * 16 + frow, fk));
      bf16x8 bv1 = *(const bf16x8*)(lVt + swzi(df * 16 + frow, 32 + fk));
      o[df] = __builtin_amdgcn_mfma_f32_16x16x32_bf16(pa0, bv0, o[df], 0, 0, 0);
      o[df] = __builtin_amdgcn_mfma_f32_16x16x32_bf16(pa1, bv1, o[df], 0, 0, 0);
    }
  }

  // epilogue: divide by l, write y
#pragma unroll
  for (int df = 0; df < 4; ++df)
#pragma unroll
    for (int qi = 0; qi < 4; ++qi) {
      int qg = q0 + w16 + qrow + qi;
      y[(size_t)(b * T + qg) * D + h * DH + df * 16 + frow] = f2b(o[df][qi] / l_r[qi]);
    }
}

// ---- per-row NLL from logits ----
__global__ __launch_bounds__(256) void k_loss_row(const float* __restrict__ logits,
                                                  const int* __restrict__ targets,
                                                  float* __restrict__ nll) {
  __shared__ float buf4[4];
  int row = blockIdx.x, tid = threadIdx.x;
  const float* lr = logits + (size_t)row * V;
  float m = -1e30f;
  for (int j = tid; j < V; j += 256) m = fmaxf(m, lr[j]);
  m = block_reduce(m, true, buf4);
  float sum = 0.f;
  for (int j = tid; j < V; j += 256) sum += __expf(lr[j] - m);
  sum = block_reduce(sum, false, buf4);
  if (tid == 0) {
    int tgt = targets[row];
    bool valid = (tgt != -100);
    nll[row] = valid ? (m + logf(sum) - lr[tgt]) : 0.f;
  }
}

__global__ __launch_bounds__(256) void k_loss_final(const float* __restrict__ nll,
                                                    const int* __restrict__ targets,
                                                    float* __restrict__ out) {
  __shared__ float buf4[4];
  float s = 0.f, c = 0.f;
  for (int i = threadIdx.x; i < M; i += 256) {
    s += nll[i];
    c += (targets[i] != -100) ? 1.f : 0.f;
  }
  s = block_reduce(s, false, buf4);
  c = block_reduce(c, false, buf4);
  if (threadIdx.x == 0) out[0] = s / fmaxf(c, 1.f);
}

extern "C" void kernel_launch(void* const* d_in, const int* in_sizes, int n_in,
                              void* d_out, int out_size, void* d_ws, size_t ws_size,
                              hipStream_t stream) {
  const int* idx       = (const int*)d_in[0];
  const int* targets   = (const int*)d_in[1];
  const float* tok     = (const float*)d_in[2];
  const float* pos     = (const float*)d_in[3];
  const float* qkv_w   = (const float*)d_in[4];
  const float* qkv_b   = (const float*)d_in[5];
  const float* proj_w  = (const float*)d_in[6];
  const float* proj_b  = (const float*)d_in[7];
  const float* fc1_w   = (const float*)d_in[8];
  const float* fc1_b   = (const float*)d_in[9];
  const float* fc2_w   = (const float*)d_in[10];
  const float* fc2_b   = (const float*)d_in[11];
  const float* ln1_w   = (const float*)d_in[12];
  const float* ln1_b   = (const float*)d_in[13];
  const float* ln2_w   = (const float*)d_in[14];
  const float* ln2_b   = (const float*)d_in[15];
  const float* lnf_w   = (const float*)d_in[16];
  const float* lnf_b   = (const float*)d_in[17];

  float* logits = (float*)d_out;

  // ---- ws layout (~35 MB) ----
  char* ws = (char*)d_ws;
  float* x  = (float*)ws;                   // M*D f32      12.58 MB
  u16* hb   = (u16*)(ws + 12582912);        // M*D bf16      6.29 MB
  u16* yb   = (u16*)(ws + 18874368);        // M*D bf16      6.29 MB
  u16* wb   = (u16*)(ws + 25165824);        // VCHUNK*D bf16 9.83 MB
  float* nll = (float*)(ws + 34996224);     // M f32        16 KB

  // ---- d_out scratch (dead before logits are written) ----
  u16* qkvb   = (u16*)logits;                        // M*D3 bf16  18.87 MB
  u16* f1b    = (u16*)(logits + 9437184);            // M*F bf16   25.17 MB
  u16* wqkv   = (u16*)(logits + 15728640);           // L*D3*D bf16
  u16* wproj  = (u16*)(logits + 22806528);           // L*D*D
  u16* wfc1   = (u16*)(logits + 25165824);           // L*F*D
  u16* wfc2   = (u16*)(logits + 34603008);           // L*D*F

  k_cvt<<<(L * D3 * D / 4 + 255) / 256, 256, 0, stream>>>(qkv_w, wqkv, L * D3 * D / 4);
  k_cvt<<<(L * D * D / 4 + 255) / 256, 256, 0, stream>>>(proj_w, wproj, L * D * D / 4);
  k_cvt<<<(L * F * D / 4 + 255) / 256, 256, 0, stream>>>(fc1_w, wfc1, L * F * D / 4);
  k_cvt<<<(L * D * F / 4 + 255) / 256, 256, 0, stream>>>(fc2_w, wfc2, L * D * F / 4);

  k_embed<<<(M * D) / 256, 256, 0, stream>>>(idx, tok, pos, x);

  for (int l = 0; l < L; ++l) {
    k_lnorm<<<M, 256, 0, stream>>>(x, ln1_w + (size_t)l * D, ln1_b + (size_t)l * D, hb);
    k_mfma_gemm<<<dim3(D3 / 128, M / 128), 256, 0, stream>>>(
        hb, wqkv + (size_t)l * D3 * D, qkv_b + (size_t)l * D3, nullptr, qkvb, D, D3, 9);
    k_fattn<<<dim3(T / 64, BATCH * H), 256, 0, stream>>>(qkvb, yb);
    k_mfma_gemm<<<dim3(D / 128, M / 128), 256, 0, stream>>>(
        yb, wproj + (size_t)l * D * D, proj_b + (size_t)l * D, x, x, D, D, 3);
    k_lnorm<<<M, 256, 0, stream>>>(x, ln2_w + (size_t)l * D, ln2_b + (size_t)l * D, hb);
    k_mfma_gemm<<<dim3(F / 128, M / 128), 256, 0, stream>>>(
        hb, wfc1 + (size_t)l * F * D, fc1_b + (size_t)l * F, nullptr, f1b, D, F, 13);
    k_mfma_gemm<<<dim3(D / 128, M / 128), 256, 0, stream>>>(
        f1b, wfc2 + (size_t)l * D * F, fc2_b + (size_t)l * D, x, x, F, D, 3);
  }

  k_lnorm<<<M, 256, 0, stream>>>(x, lnf_w, lnf_b, hb);
  for (int c = 0; c < 5; ++c) {
    k_cvt<<<(VCHUNK * D / 4 + 255) / 256, 256, 0, stream>>>(
        tok + (size_t)c * VCHUNK * D, wb, VCHUNK * D / 4);
    k_mfma_gemm<<<dim3(VCHUNK / 128, M / 128), 256, 0, stream>>>(
        hb, wb, nullptr, nullptr, logits + (size_t)c * VCHUNK, D, V, 0);
  }
  k_loss_row<<<M, 256, 0, stream>>>(logits, targets, nll);
  k_loss_final<<<1, 256, 0, stream>>>(nll, targets, logits + (size_t)M * V);
}

// Round 4
// 2769.189 us; speedup vs baseline: 6.8612x; 1.0780x over previous
//
#include <hip/hip_runtime.h>
#include <hip/hip_bf16.h>
#include <math.h>

#define BATCH 4
#define T 1024
#define D 768
#define L 8
#define H 12
#define F 3072
#define V 32000
#define DH 64
#define M (BATCH*T)   // 4096
#define D3 (3*D)      // 2304
#define SCALE 0.125f
#define VCHUNK 6400   // lm_head N-chunk (25 tiles of 256)
#define PBT 125       // total col-partial blocks (32000/256)

typedef unsigned short u16;
typedef __attribute__((ext_vector_type(8))) short bf16x8;
typedef __attribute__((ext_vector_type(4))) float f32x4;

__device__ inline u16 f2b(float f) {
  __hip_bfloat16 h = __float2bfloat16(f);
  return *(u16*)&h;
}

// async global->LDS, 16B per lane; LDS dest is wave-uniform base + lane*16
__device__ inline void gll16(const void* g, void* l) {
  __builtin_amdgcn_global_load_lds(
      (const __attribute__((address_space(1))) unsigned int*)g,
      (__attribute__((address_space(3))) unsigned int*)l, 16, 0, 0);
}

// XOR swizzle for [*][64] u16 LDS tiles (manual-write paths)
__device__ inline int swzi(int r, int c) {
  return (r * 64 + c) ^ ((((r & 7) ^ ((r >> 3) & 7))) << 3);
}

// ---- block-wide reduce (exactly 256 threads / 4 waves) ----
__device__ inline float block_reduce(float v, bool is_max, float* buf4) {
  int lane = threadIdx.x & 63, wid = threadIdx.x >> 6;
#pragma unroll
  for (int off = 32; off; off >>= 1) {
    float o = __shfl_down(v, off, 64);
    v = is_max ? fmaxf(v, o) : v + o;
  }
  if (lane == 0) buf4[wid] = v;
  __syncthreads();
  float r = is_max ? fmaxf(fmaxf(buf4[0], buf4[1]), fmaxf(buf4[2], buf4[3]))
                   : buf4[0] + buf4[1] + buf4[2] + buf4[3];
  __syncthreads();
  return r;
}

// ---- x = tok_emb[idx] + pos_emb ----
__global__ __launch_bounds__(256) void k_embed(const int* __restrict__ idx,
                                               const float* __restrict__ tok,
                                               const float* __restrict__ pos,
                                               float* __restrict__ x) {
  int i = blockIdx.x * 256 + threadIdx.x;
  int row = i / D, d = i - row * D;
  int t = row & (T - 1);
  x[i] = tok[(size_t)idx[row] * D + d] + pos[(size_t)t * D + d];
}

// ---- f32 -> bf16 convert, 4 elems/thread ----
__global__ __launch_bounds__(256) void k_cvt(const float* __restrict__ in,
                                             u16* __restrict__ out, int n4) {
  int i = blockIdx.x * 256 + threadIdx.x;
  if (i >= n4) return;
  float4 v = ((const float4*)in)[i];
  ushort4 o;
  o.x = f2b(v.x); o.y = f2b(v.y); o.z = f2b(v.z); o.w = f2b(v.w);
  ((ushort4*)out)[i] = o;
}

// ---- LayerNorm: one block per row of 768, bf16 out ----
__global__ __launch_bounds__(256) void k_lnorm(const float* __restrict__ x,
                                               const float* __restrict__ w,
                                               const float* __restrict__ b,
                                               u16* __restrict__ out) {
  __shared__ float buf4[4];
  int row = blockIdx.x, tid = threadIdx.x;
  const float* xr = x + (size_t)row * D;
  float v0 = xr[tid], v1 = xr[tid + 256], v2 = xr[tid + 512];
  float s = v0 + v1 + v2;
  float ss = v0 * v0 + v1 * v1 + v2 * v2;
  s = block_reduce(s, false, buf4);
  ss = block_reduce(ss, false, buf4);
  float mu = s * (1.0f / D);
  float var = ss * (1.0f / D) - mu * mu;
  float rs = rsqrtf(var + 1e-5f);
  u16* orow = out + (size_t)row * D;
  orow[tid]       = f2b((v0 - mu) * rs * w[tid]       + b[tid]);
  orow[tid + 256] = f2b((v1 - mu) * rs * w[tid + 256] + b[tid + 256]);
  orow[tid + 512] = f2b((v2 - mu) * rs * w[tid + 512] + b[tid + 512]);
}

// ---- MFMA GEMM: C[M,N] = A[M,K] @ W[N,K]^T, bf16 in, f32 acc ----
// flags: 1=bias, 2=residual add (f32), 4=exact gelu, 8=bf16 output
__global__ __launch_bounds__(256) void k_mfma_gemm(
    const u16* __restrict__ A, const u16* __restrict__ W,
    const float* __restrict__ bias, const float* __restrict__ resid,
    void* __restrict__ Cout, int K, int ldC, int flags) {
  __shared__ __attribute__((aligned(16))) u16 lA[128 * 32];
  __shared__ __attribute__((aligned(16))) u16 lB[128 * 32];
  int tid = threadIdx.x;
  int w = tid >> 6, lane = tid & 63;
  int bn = blockIdx.x, bm = blockIdx.y;
  const u16* Ab = A + (size_t)bm * 128 * K;
  const u16* Wb = W + (size_t)bn * 128 * K;
  int r0 = w * 16 + (lane >> 2);
  int r1 = 64 + r0;
  int kc = (lane & 3) * 8;
  int wr = (w >> 1) * 64, wc = (w & 1) * 64;
  int frow = lane & 15, fk = (lane >> 4) * 8;
  f32x4 acc[4][4];
#pragma unroll
  for (int i = 0; i < 4; ++i)
#pragma unroll
    for (int j = 0; j < 4; ++j) acc[i][j] = (f32x4)(0.f);

  for (int k0 = 0; k0 < K; k0 += 32) {
    __syncthreads();
    gll16(Ab + (size_t)r0 * K + k0 + kc, lA + w * 512);
    gll16(Ab + (size_t)r1 * K + k0 + kc, lA + (w + 4) * 512);
    gll16(Wb + (size_t)r0 * K + k0 + kc, lB + w * 512);
    gll16(Wb + (size_t)r1 * K + k0 + kc, lB + (w + 4) * 512);
    __syncthreads();
    bf16x8 af[4], bfr[4];
#pragma unroll
    for (int i = 0; i < 4; ++i)
      af[i] = *(const bf16x8*)(lA + (wr + i * 16 + frow) * 32 + fk);
#pragma unroll
    for (int j = 0; j < 4; ++j)
      bfr[j] = *(const bf16x8*)(lB + (wc + j * 16 + frow) * 32 + fk);
#pragma unroll
    for (int i = 0; i < 4; ++i)
#pragma unroll
      for (int j = 0; j < 4; ++j)
        acc[i][j] = __builtin_amdgcn_mfma_f32_16x16x32_bf16(af[i], bfr[j], acc[i][j], 0, 0, 0);
  }

  int m0 = bm * 128 + wr + (lane >> 4) * 4;
  int n0 = bn * 128 + wc + (lane & 15);
#pragma unroll
  for (int i = 0; i < 4; ++i) {
#pragma unroll
    for (int j = 0; j < 4; ++j) {
      int n = n0 + j * 16;
      float bv = (flags & 1) ? bias[n] : 0.f;
#pragma unroll
      for (int q = 0; q < 4; ++q) {
        int m = m0 + i * 16 + q;
        size_t off = (size_t)m * ldC + n;
        float v = acc[i][j][q] + bv;
        if (flags & 4) v = 0.5f * v * (1.0f + erff(v * 0.70710678118f));
        if (flags & 2) v += resid[off];
        if (flags & 8) ((u16*)Cout)[off] = f2b(v);
        else           ((float*)Cout)[off] = v;
      }
    }
  }
}

// ---- lm_head 256x256 GEMM, K=768 fixed, 8 waves, dbuf + 4-phase + fused LSE ----
__global__ __launch_bounds__(512, 2) void k_lm256(
    const u16* __restrict__ A,   // [4096][768] bf16
    const u16* __restrict__ B,   // [VCHUNK][768] bf16
    float* __restrict__ C,       // logits [4096][V]
    float* __restrict__ pm, float* __restrict__ ps,  // [4096][PBT]
    int gc0) {                   // global col offset of this chunk
  __shared__ __attribute__((aligned(16))) u16 lds[2][2][2][128 * 64];
  __shared__ float pml[256][4], psl[256][4];
  const int K = 768, NT = 12;
  int tid = threadIdx.x, w = tid >> 6, lane = tid & 63;
  int wm = w >> 2, wn = w & 3;
  int bm = blockIdx.y, bn = blockIdx.x;
  int frow = lane & 15, g = lane >> 4;
  int sr = lane >> 3, scu = lane & 7;
  const u16* Abase = A + (size_t)bm * 256 * K;
  const u16* Bbase = B + (size_t)bn * 256 * K;

  f32x4 acc[8][4];
#pragma unroll
  for (int i = 0; i < 8; ++i)
#pragma unroll
    for (int j = 0; j < 4; ++j) acc[i][j] = (f32x4)(0.f);

  // stage half-tile h of K-tile t.  h: 0=A-lo 1=A-hi 2=B-lo 3=B-hi
#define STAGE(t, h)                                                       \
  {                                                                       \
    const u16* src = ((h) < 2 ? Abase : Bbase) + (size_t)(((h)&1) * 128) * K; \
    u16* dst = &lds[(t) & 1][(h) >> 1][(h)&1][0];                         \
    _Pragma("unroll") for (int rr = 0; rr < 2; ++rr) {                    \
      int row = rr * 64 + w * 8 + sr;                                     \
      int gcu = scu ^ (row & 7);                                          \
      gll16(src + (size_t)row * K + (t) * 64 + gcu * 8,                   \
            dst + (rr * 64 + w * 8) * 64);                                \
    }                                                                     \
  }

  bf16x8 ar[8], br[8];
#define LDA(T_, ILO)                                                      \
  {                                                                       \
    const u16* base = &lds[(T_)&1][0][wm][0];                             \
    _Pragma("unroll") for (int ii = 0; ii < 4; ++ii)                      \
    _Pragma("unroll") for (int kk = 0; kk < 2; ++kk) {                    \
      int ri = ((ILO) + ii) * 16 + frow;                                  \
      int u = (g + kk * 4) ^ (ri & 7);                                    \
      ar[ii * 2 + kk] = *(const bf16x8*)(base + ri * 64 + u * 8);         \
    }                                                                     \
  }
#define LDB(T_, JLO, BO)                                                  \
  {                                                                       \
    const u16* base = &lds[(T_)&1][1][wn >> 1][0];                        \
    _Pragma("unroll") for (int jj = 0; jj < 2; ++jj)                      \
    _Pragma("unroll") for (int kk = 0; kk < 2; ++kk) {                    \
      int rj = (wn & 1) * 64 + ((JLO) + jj) * 16 + frow;                  \
      int u = (g + kk * 4) ^ (rj & 7);                                    \
      br[(BO) + jj * 2 + kk] = *(const bf16x8*)(base + rj * 64 + u * 8);  \
    }                                                                     \
  }
#define MFMA16(ILO, JLO, BO)                                              \
  _Pragma("unroll") for (int ii = 0; ii < 4; ++ii)                        \
  _Pragma("unroll") for (int jj = 0; jj < 2; ++jj)                        \
  _Pragma("unroll") for (int kk = 0; kk < 2; ++kk)                        \
    acc[(ILO) + ii][(JLO) + jj] = __builtin_amdgcn_mfma_f32_16x16x32_bf16( \
        ar[ii * 2 + kk], br[(BO) + jj * 2 + kk], acc[(ILO) + ii][(JLO) + jj], 0, 0, 0);

  // prologue: tile 0 fully staged
  STAGE(0, 0); STAGE(0, 1); STAGE(0, 2); STAGE(0, 3);
  asm volatile("s_waitcnt vmcnt(0)");
  __builtin_amdgcn_s_barrier();

  for (int t = 0; t < NT; ++t) {
    bool pf = (t + 1 < NT);
    // phase A: a-lo + b-lo, compute Q(0,0)
    LDA(t, 0); LDB(t, 0, 0);
    if (pf) STAGE(t + 1, 0);
    __builtin_amdgcn_s_setprio(1);
    MFMA16(0, 0, 0);
    __builtin_amdgcn_s_setprio(0);
    __builtin_amdgcn_s_barrier();
    // phase B: b-hi, compute Q(0,1)
    LDB(t, 2, 4);
    if (pf) STAGE(t + 1, 1);
    __builtin_amdgcn_s_setprio(1);
    MFMA16(0, 2, 4);
    __builtin_amdgcn_s_setprio(0);
    __builtin_amdgcn_s_barrier();
    // phase C: a-hi, compute Q(1,1)
    LDA(t, 4);
    if (pf) STAGE(t + 1, 2);
    __builtin_amdgcn_s_setprio(1);
    MFMA16(4, 2, 4);
    __builtin_amdgcn_s_setprio(0);
    __builtin_amdgcn_s_barrier();
    // phase D: compute Q(1,0); then swap buffers
    if (pf) STAGE(t + 1, 3);
    __builtin_amdgcn_s_setprio(1);
    MFMA16(4, 0, 0);
    __builtin_amdgcn_s_setprio(0);
    asm volatile("s_waitcnt vmcnt(0)");
    __builtin_amdgcn_s_barrier();
  }

  // epilogue: logits store + per-row (max, sumexp) partials over 256 cols
#pragma unroll
  for (int ii = 0; ii < 8; ++ii) {
#pragma unroll
    for (int q = 0; q < 4; ++q) {
      float mx = fmaxf(fmaxf(acc[ii][0][q], acc[ii][1][q]),
                       fmaxf(acc[ii][2][q], acc[ii][3][q]));
      mx = fmaxf(mx, __shfl_xor(mx, 1, 64));
      mx = fmaxf(mx, __shfl_xor(mx, 2, 64));
      mx = fmaxf(mx, __shfl_xor(mx, 4, 64));
      mx = fmaxf(mx, __shfl_xor(mx, 8, 64));
      float sm = 0.f;
#pragma unroll
      for (int jj = 0; jj < 4; ++jj) sm += __expf(acc[ii][jj][q] - mx);
      sm += __shfl_xor(sm, 1, 64);
      sm += __shfl_xor(sm, 2, 64);
      sm += __shfl_xor(sm, 4, 64);
      sm += __shfl_xor(sm, 8, 64);
      int lrow = wm * 128 + ii * 16 + g * 4 + q;
      if (frow == 0) { pml[lrow][wn] = mx; psl[lrow][wn] = sm; }
      size_t off = (size_t)(bm * 256 + lrow) * V + gc0 + bn * 256 + wn * 64 + frow;
#pragma unroll
      for (int jj = 0; jj < 4; ++jj) C[off + jj * 16] = acc[ii][jj][q];
    }
  }
  __syncthreads();
  if (tid < 256) {
    float m = fmaxf(fmaxf(pml[tid][0], pml[tid][1]), fmaxf(pml[tid][2], pml[tid][3]));
    float s = 0.f;
#pragma unroll
    for (int w4 = 0; w4 < 4; ++w4) s += psl[tid][w4] * __expf(pml[tid][w4] - m);
    size_t grow = bm * 256 + tid;
    int pb = gc0 / 256 + bn;
    pm[grow * PBT + pb] = m;
    ps[grow * PBT + pb] = s;
  }
#undef STAGE
#undef LDA
#undef LDB
#undef MFMA16
}

// ---- MFMA flash attention: qkv bf16 [M,2304] -> y bf16 [M,768] ----
// block = 128 q-rows x (b,h); wave w owns strips {w*16, 64+w*16} (16 rows each)
__global__ __launch_bounds__(256) void k_fattn(const u16* __restrict__ qkv,
                                               u16* __restrict__ y) {
  __shared__ __attribute__((aligned(16))) u16 lQ[128 * 64];
  __shared__ __attribute__((aligned(16))) u16 lK[64 * 64];
  __shared__ __attribute__((aligned(16))) u16 lVt[64 * 64];  // swizzled, Vt[d][k]
  __shared__ __attribute__((aligned(16))) u16 lP[128 * 64];  // swizzled, P[q][k]
  int tid = threadIdx.x;
  int w = tid >> 6, lane = tid & 63;
  int qtb = blockIdx.x;
  int bh = blockIdx.y, b = bh / H, h = bh - b * H;
  int q0 = qtb * 128;
  const u16* base = qkv + (size_t)b * T * D3 + h * DH;
  int srow = lane >> 3;            // 0..7
  int scu = lane & 7;              // col unit (8 elems)
  int frow = lane & 15, g = lane >> 4;
  int w16 = w * 16;
  int qrow = g * 4;

  // stage Q tile (128 rows), swizzled source so LDS(r,u)=G(r,u^(r&7))
#pragma unroll
  for (int c = 0; c < 4; ++c) {
    int row = c * 32 + w * 8 + srow;
    int gcu = scu ^ (row & 7);
    gll16(base + (size_t)(q0 + row) * D3 + gcu * 8, lQ + (c * 32 + w * 8) * 64);
  }

  float m_r[2][4], l_r[2][4];
  f32x4 o[2][4];
#pragma unroll
  for (int s = 0; s < 2; ++s)
#pragma unroll
    for (int i = 0; i < 4; ++i) {
      m_r[s][i] = -1e30f; l_r[s][i] = 0.f; o[s][i] = (f32x4)(0.f);
    }

  int ktmax = 2 * qtb + 1;
  for (int kt = 0; kt <= ktmax; ++kt) {
    __syncthreads();  // prev-iter LDS reads done (and Q staging on iter 0)
    int k0 = kt * 64;
    // stage K tile (swizzled source)
#pragma unroll
    for (int c = 0; c < 2; ++c) {
      int row = c * 32 + w * 8 + srow;
      int gcu = scu ^ (row & 7);
      gll16(base + D + (size_t)(k0 + row) * D3 + gcu * 8, lK + (c * 32 + w * 8) * 64);
    }
    // stage V transposed (reg transpose, swizzled writes)
#pragma unroll
    for (int p = 0; p < 2; ++p) {
      int kk = p * 32 + w * 8 + srow;
      uint4 vv = *(const uint4*)(base + 2 * D + (size_t)(k0 + kk) * D3 + scu * 8);
      unsigned vals[4] = {vv.x, vv.y, vv.z, vv.w};
#pragma unroll
      for (int e = 0; e < 4; ++e) {
        lVt[swzi(scu * 8 + 2 * e, kk)]     = (u16)(vals[e] & 0xffff);
        lVt[swzi(scu * 8 + 2 * e + 1, kk)] = (u16)(vals[e] >> 16);
      }
    }
    __syncthreads();

#pragma unroll
    for (int s = 0; s < 2; ++s) {
      if (kt > 2 * qtb + s) continue;  // strip fully masked
      int qs = s * 64 + w16;
      int f7 = frow & 7;
      // S = Q K^T (16 x 64), swizzled reads
      bf16x8 aq0 = *(const bf16x8*)(lQ + (qs + frow) * 64 + (g ^ f7) * 8);
      bf16x8 aq1 = *(const bf16x8*)(lQ + (qs + frow) * 64 + ((g + 4) ^ f7) * 8);
      f32x4 sv[4];
#pragma unroll
      for (int kn = 0; kn < 4; ++kn) {
        bf16x8 bk0 = *(const bf16x8*)(lK + (kn * 16 + frow) * 64 + (g ^ f7) * 8);
        bf16x8 bk1 = *(const bf16x8*)(lK + (kn * 16 + frow) * 64 + ((g + 4) ^ f7) * 8);
        sv[kn] = __builtin_amdgcn_mfma_f32_16x16x32_bf16(aq0, bk0, (f32x4)(0.f), 0, 0, 0);
        sv[kn] = __builtin_amdgcn_mfma_f32_16x16x32_bf16(aq1, bk1, sv[kn], 0, 0, 0);
      }
      // scale + causal mask (diagonal tile only)
#pragma unroll
      for (int kn = 0; kn < 4; ++kn)
#pragma unroll
        for (int qi = 0; qi < 4; ++qi) {
          float v = sv[kn][qi] * SCALE;
          if (kt == 2 * qtb + s) {
            int qg = q0 + qs + qrow + qi;
            int kg = k0 + kn * 16 + frow;
            if (kg > qg) v = -1e30f;
          }
          sv[kn][qi] = v;
        }
      // online softmax
#pragma unroll
      for (int qi = 0; qi < 4; ++qi) {
        float rm = fmaxf(fmaxf(sv[0][qi], sv[1][qi]), fmaxf(sv[2][qi], sv[3][qi]));
        rm = fmaxf(rm, __shfl_xor(rm, 1, 64));
        rm = fmaxf(rm, __shfl_xor(rm, 2, 64));
        rm = fmaxf(rm, __shfl_xor(rm, 4, 64));
        rm = fmaxf(rm, __shfl_xor(rm, 8, 64));
        float mn = fmaxf(m_r[s][qi], rm);
        float alpha = __expf(m_r[s][qi] - mn);
        m_r[s][qi] = mn;
        float rs = 0.f;
#pragma unroll
        for (int kn = 0; kn < 4; ++kn) {
          float p = __expf(sv[kn][qi] - mn);
          sv[kn][qi] = p;
          rs += p;
        }
        rs += __shfl_xor(rs, 1, 64);
        rs += __shfl_xor(rs, 2, 64);
        rs += __shfl_xor(rs, 4, 64);
        rs += __shfl_xor(rs, 8, 64);
        l_r[s][qi] = l_r[s][qi] * alpha + rs;
#pragma unroll
        for (int df = 0; df < 4; ++df) o[s][df][qi] *= alpha;
      }
      // P -> LDS (wave-private rows, swizzled)
#pragma unroll
      for (int kn = 0; kn < 4; ++kn)
#pragma unroll
        for (int qi = 0; qi < 4; ++qi)
          lP[swzi(qs + qrow + qi, kn * 16 + frow)] = f2b(sv[kn][qi]);
      // P.Vt MFMA (same-wave LDS RAW)
      bf16x8 pa0 = *(const bf16x8*)(lP + swzi(qs + frow, g * 8));
      bf16x8 pa1 = *(const bf16x8*)(lP + swzi(qs + frow, 32 + g * 8));
#pragma unroll
      for (int df = 0; df < 4; ++df) {
        bf16x8 bv0 = *(const bf16x8*)(lVt + swzi(df * 16 + frow, g * 8));
        bf16x8 bv1 = *(const bf16x8*)(lVt + swzi(df * 16 + frow, 32 + g * 8));
        o[s][df] = __builtin_amdgcn_mfma_f32_16x16x32_bf16(pa0, bv0, o[s][df], 0, 0, 0);
        o[s][df] = __builtin_amdgcn_mfma_f32_16x16x32_bf16(pa1, bv1, o[s][df], 0, 0, 0);
      }
    }
  }

  // epilogue
#pragma unroll
  for (int s = 0; s < 2; ++s)
#pragma unroll
    for (int df = 0; df < 4; ++df)
#pragma unroll
      for (int qi = 0; qi < 4; ++qi) {
        int qg = q0 + s * 64 + w16 + qrow + qi;
        y[(size_t)(b * T + qg) * D + h * DH + df * 16 + frow] =
            f2b(o[s][df][qi] / l_r[s][qi]);
      }
}

// ---- final LSE + NLL from partials; one wave per row ----
__global__ __launch_bounds__(256) void k_loss_rows(
    const float* __restrict__ pm, const float* __restrict__ ps,
    const float* __restrict__ logits, const int* __restrict__ targets,
    float* __restrict__ nll) {
  int lane = threadIdx.x & 63, wid = threadIdx.x >> 6;
  int row = blockIdx.x * 4 + wid;
  const float* pmr = pm + (size_t)row * PBT;
  const float* psr = ps + (size_t)row * PBT;
  float m = -1e30f;
  for (int i = lane; i < PBT; i += 64) m = fmaxf(m, pmr[i]);
#pragma unroll
  for (int off = 32; off; off >>= 1) m = fmaxf(m, __shfl_xor(m, off, 64));
  float s = 0.f;
  for (int i = lane; i < PBT; i += 64) s += psr[i] * __expf(pmr[i] - m);
#pragma unroll
  for (int off = 32; off; off >>= 1) s += __shfl_xor(s, off, 64);
  if (lane == 0) {
    int tgt = targets[row];
    nll[row] = (tgt != -100) ? (m + logf(s) - logits[(size_t)row * V + tgt]) : 0.f;
  }
}

__global__ __launch_bounds__(256) void k_loss_final(const float* __restrict__ nll,
                                                    const int* __restrict__ targets,
                                                    float* __restrict__ out) {
  __shared__ float buf4[4];
  float s = 0.f, c = 0.f;
  for (int i = threadIdx.x; i < M; i += 256) {
    s += nll[i];
    c += (targets[i] != -100) ? 1.f : 0.f;
  }
  s = block_reduce(s, false, buf4);
  c = block_reduce(c, false, buf4);
  if (threadIdx.x == 0) out[0] = s / fmaxf(c, 1.f);
}

extern "C" void kernel_launch(void* const* d_in, const int* in_sizes, int n_in,
                              void* d_out, int out_size, void* d_ws, size_t ws_size,
                              hipStream_t stream) {
  const int* idx       = (const int*)d_in[0];
  const int* targets   = (const int*)d_in[1];
  const float* tok     = (const float*)d_in[2];
  const float* pos     = (const float*)d_in[3];
  const float* qkv_w   = (const float*)d_in[4];
  const float* qkv_b   = (const float*)d_in[5];
  const float* proj_w  = (const float*)d_in[6];
  const float* proj_b  = (const float*)d_in[7];
  const float* fc1_w   = (const float*)d_in[8];
  const float* fc1_b   = (const float*)d_in[9];
  const float* fc2_w   = (const float*)d_in[10];
  const float* fc2_b   = (const float*)d_in[11];
  const float* ln1_w   = (const float*)d_in[12];
  const float* ln1_b   = (const float*)d_in[13];
  const float* ln2_w   = (const float*)d_in[14];
  const float* ln2_b   = (const float*)d_in[15];
  const float* lnf_w   = (const float*)d_in[16];
  const float* lnf_b   = (const float*)d_in[17];

  float* logits = (float*)d_out;

  // ---- ws layout (~39.1 MB) ----
  char* ws = (char*)d_ws;
  float* x   = (float*)ws;                  // M*D f32        12.58 MB
  u16* hb    = (u16*)(ws + 12582912);       // M*D bf16        6.29 MB
  u16* yb    = (u16*)(ws + 18874368);       // M*D bf16        6.29 MB
  u16* wb    = (u16*)(ws + 25165824);       // VCHUNK*D bf16   9.83 MB
  float* pm  = (float*)(ws + 34996224);     // M*PBT f32       2.05 MB
  float* ps  = (float*)(ws + 37044224);     // M*PBT f32       2.05 MB
  float* nll = (float*)(ws + 39092224);     // M f32           16 KB

  // ---- d_out scratch (dead before logits are written) ----
  u16* qkvb   = (u16*)logits;                        // M*D3 bf16
  u16* f1b    = (u16*)(logits + 9437184);            // M*F bf16
  u16* wqkv   = (u16*)(logits + 15728640);
  u16* wproj  = (u16*)(logits + 22806528);
  u16* wfc1   = (u16*)(logits + 25165824);
  u16* wfc2   = (u16*)(logits + 34603008);

  k_cvt<<<(L * D3 * D / 4 + 255) / 256, 256, 0, stream>>>(qkv_w, wqkv, L * D3 * D / 4);
  k_cvt<<<(L * D * D / 4 + 255) / 256, 256, 0, stream>>>(proj_w, wproj, L * D * D / 4);
  k_cvt<<<(L * F * D / 4 + 255) / 256, 256, 0, stream>>>(fc1_w, wfc1, L * F * D / 4);
  k_cvt<<<(L * D * F / 4 + 255) / 256, 256, 0, stream>>>(fc2_w, wfc2, L * D * F / 4);

  k_embed<<<(M * D) / 256, 256, 0, stream>>>(idx, tok, pos, x);

  for (int l = 0; l < L; ++l) {
    k_lnorm<<<M, 256, 0, stream>>>(x, ln1_w + (size_t)l * D, ln1_b + (size_t)l * D, hb);
    k_mfma_gemm<<<dim3(D3 / 128, M / 128), 256, 0, stream>>>(
        hb, wqkv + (size_t)l * D3 * D, qkv_b + (size_t)l * D3, nullptr, qkvb, D, D3, 9);
    k_fattn<<<dim3(T / 128, BATCH * H), 256, 0, stream>>>(qkvb, yb);
    k_mfma_gemm<<<dim3(D / 128, M / 128), 256, 0, stream>>>(
        yb, wproj + (size_t)l * D * D, proj_b + (size_t)l * D, x, x, D, D, 3);
    k_lnorm<<<M, 256, 0, stream>>>(x, ln2_w + (size_t)l * D, ln2_b + (size_t)l * D, hb);
    k_mfma_gemm<<<dim3(F / 128, M / 128), 256, 0, stream>>>(
        hb, wfc1 + (size_t)l * F * D, fc1_b + (size_t)l * F, nullptr, f1b, D, F, 13);
    k_mfma_gemm<<<dim3(D / 128, M / 128), 256, 0, stream>>>(
        f1b, wfc2 + (size_t)l * D * F, fc2_b + (size_t)l * D, x, x, F, D, 3);
  }

  k_lnorm<<<M, 256, 0, stream>>>(x, lnf_w, lnf_b, hb);
  for (int c = 0; c < 5; ++c) {
    k_cvt<<<(VCHUNK * D / 4 + 255) / 256, 256, 0, stream>>>(
        tok + (size_t)c * VCHUNK * D, wb, VCHUNK * D / 4);
    k_lm256<<<dim3(VCHUNK / 256, M / 256), 512, 0, stream>>>(
        hb, wb, logits, pm, ps, c * VCHUNK);
  }
  k_loss_rows<<<M / 4, 256, 0, stream>>>(pm, ps, logits, targets, nll);
  k_loss_final<<<1, 256, 0, stream>>>(nll, targets, logits + (size_t)M * V);
}

// Round 5
// 2169.332 us; speedup vs baseline: 8.7585x; 1.2765x over previous
//
#include <hip/hip_runtime.h>
#include <hip/hip_bf16.h>
#include <math.h>

#define BATCH 4
#define T 1024
#define D 768
#define L 8
#define H 12
#define F 3072
#define V 32000
#define DH 64
#define M (BATCH*T)   // 4096
#define D3 (3*D)      // 2304
#define SCALE 0.125f
#define VCHUNK 6400   // lm_head N-chunk (25 tiles of 256)
#define PBT 125       // total col-partial blocks (32000/256)

typedef unsigned short u16;
typedef __attribute__((ext_vector_type(8))) short bf16x8;
typedef __attribute__((ext_vector_type(4))) float f32x4;

__device__ inline u16 f2b(float f) {
  __hip_bfloat16 h = __float2bfloat16(f);
  return *(u16*)&h;
}

// async global->LDS, 16B per lane; LDS dest is wave-uniform base + lane*16
__device__ inline void gll16(const void* g, void* l) {
  __builtin_amdgcn_global_load_lds(
      (const __attribute__((address_space(1))) unsigned int*)g,
      (__attribute__((address_space(3))) unsigned int*)l, 16, 0, 0);
}

// XOR swizzle for [*][64] u16 LDS tiles (manual-write paths)
__device__ inline int swzi(int r, int c) {
  return (r * 64 + c) ^ ((((r & 7) ^ ((r >> 3) & 7))) << 3);
}

// ---- block-wide reduce (exactly 256 threads / 4 waves) ----
__device__ inline float block_reduce(float v, bool is_max, float* buf4) {
  int lane = threadIdx.x & 63, wid = threadIdx.x >> 6;
#pragma unroll
  for (int off = 32; off; off >>= 1) {
    float o = __shfl_down(v, off, 64);
    v = is_max ? fmaxf(v, o) : v + o;
  }
  if (lane == 0) buf4[wid] = v;
  __syncthreads();
  float r = is_max ? fmaxf(fmaxf(buf4[0], buf4[1]), fmaxf(buf4[2], buf4[3]))
                   : buf4[0] + buf4[1] + buf4[2] + buf4[3];
  __syncthreads();
  return r;
}

// ---- x = tok_emb[idx] + pos_emb ----
__global__ __launch_bounds__(256) void k_embed(const int* __restrict__ idx,
                                               const float* __restrict__ tok,
                                               const float* __restrict__ pos,
                                               float* __restrict__ x) {
  int i = blockIdx.x * 256 + threadIdx.x;
  int row = i / D, d = i - row * D;
  int t = row & (T - 1);
  x[i] = tok[(size_t)idx[row] * D + d] + pos[(size_t)t * D + d];
}

// ---- f32 -> bf16 convert, 4 elems/thread ----
__global__ __launch_bounds__(256) void k_cvt(const float* __restrict__ in,
                                             u16* __restrict__ out, int n4) {
  int i = blockIdx.x * 256 + threadIdx.x;
  if (i >= n4) return;
  float4 v = ((const float4*)in)[i];
  ushort4 o;
  o.x = f2b(v.x); o.y = f2b(v.y); o.z = f2b(v.z); o.w = f2b(v.w);
  ((ushort4*)out)[i] = o;
}

// ---- LayerNorm: one WAVE per row of 768, bf16 out; no LDS, no barriers ----
__global__ __launch_bounds__(256) void k_lnorm(const float* __restrict__ x,
                                               const float* __restrict__ w,
                                               const float* __restrict__ b,
                                               u16* __restrict__ out) {
  int lane = threadIdx.x & 63, wid = threadIdx.x >> 6;
  int row = blockIdx.x * 4 + wid;
  const float4* xr = (const float4*)(x + (size_t)row * D);
  float4 v[3];
  float s = 0.f, ss = 0.f;
#pragma unroll
  for (int p = 0; p < 3; ++p) {
    v[p] = xr[lane + 64 * p];
    s += v[p].x + v[p].y + v[p].z + v[p].w;
    ss += v[p].x * v[p].x + v[p].y * v[p].y + v[p].z * v[p].z + v[p].w * v[p].w;
  }
#pragma unroll
  for (int off = 32; off; off >>= 1) {
    s += __shfl_xor(s, off, 64);
    ss += __shfl_xor(ss, off, 64);
  }
  float mu = s * (1.0f / D);
  float var = ss * (1.0f / D) - mu * mu;
  float rs = rsqrtf(var + 1e-5f);
  ushort4* orow = (ushort4*)(out + (size_t)row * D);
#pragma unroll
  for (int p = 0; p < 3; ++p) {
    float4 wv = ((const float4*)w)[lane + 64 * p];
    float4 bv = ((const float4*)b)[lane + 64 * p];
    ushort4 o;
    o.x = f2b((v[p].x - mu) * rs * wv.x + bv.x);
    o.y = f2b((v[p].y - mu) * rs * wv.y + bv.y);
    o.z = f2b((v[p].z - mu) * rs * wv.z + bv.z);
    o.w = f2b((v[p].w - mu) * rs * wv.w + bv.w);
    orow[lane + 64 * p] = o;
  }
}

// ---- layer GEMM: C[M,N] = A[M,K] @ W[N,K]^T, 128x128 tile, 8 waves,
//      BK=64 double-buffered, counted vmcnt(4) pipeline, swizzled LDS ----
// flags: 1=bias, 2=residual add (f32), 4=exact gelu, 8=bf16 output
__global__ __launch_bounds__(512, 2) void k_gemm8(
    const u16* __restrict__ A, const u16* __restrict__ W,
    const float* __restrict__ bias, const float* __restrict__ resid,
    void* __restrict__ Cout, int K, int ldC, int flags) {
  __shared__ __attribute__((aligned(16))) u16 lds[2][2][128 * 64];
  int tid = threadIdx.x, w = tid >> 6, lane = tid & 63;
  int wm = w >> 2, wn = w & 3;
  int bn = blockIdx.x, bm = blockIdx.y;
  int frow = lane & 15, g = lane >> 4;
  int sr = lane >> 3, scu = lane & 7;
  const u16* Ab = A + (size_t)bm * 128 * K;
  const u16* Wb = W + (size_t)bn * 128 * K;
  int NT = K >> 6;

  f32x4 acc[4][2];
#pragma unroll
  for (int i = 0; i < 4; ++i)
#pragma unroll
    for (int j = 0; j < 2; ++j) acc[i][j] = (f32x4)(0.f);

  // stage K-tile t: each wave issues 4 gll16 (A x2 rounds, B x2 rounds)
#define STG(t)                                                            \
  {                                                                       \
    _Pragma("unroll") for (int rr = 0; rr < 2; ++rr) {                    \
      int row = rr * 64 + w * 8 + sr;                                     \
      int gcu = scu ^ (row & 7);                                          \
      gll16(Ab + (size_t)row * K + (t) * 64 + gcu * 8,                    \
            &lds[(t) & 1][0][(rr * 64 + w * 8) * 64]);                    \
      gll16(Wb + (size_t)row * K + (t) * 64 + gcu * 8,                    \
            &lds[(t) & 1][1][(rr * 64 + w * 8) * 64]);                    \
    }                                                                     \
  }

  STG(0);
  asm volatile("s_waitcnt vmcnt(0)");
  __builtin_amdgcn_s_barrier();

  for (int t = 0; t < NT; ++t) {
    if (t + 1 < NT) {
      STG(t + 1);                          // next tile into other buffer
      asm volatile("s_waitcnt vmcnt(4)");  // tile t landed; t+1 stays in flight
    } else {
      asm volatile("s_waitcnt vmcnt(0)");
    }
    __builtin_amdgcn_s_barrier();
    const u16* bA = &lds[t & 1][0][0];
    const u16* bB = &lds[t & 1][1][0];
    bf16x8 ar[8], br[4];
#pragma unroll
    for (int i = 0; i < 4; ++i)
#pragma unroll
      for (int kk = 0; kk < 2; ++kk) {
        int r = wm * 64 + i * 16 + frow;
        ar[i * 2 + kk] = *(const bf16x8*)(bA + r * 64 + ((g + kk * 4) ^ (r & 7)) * 8);
      }
#pragma unroll
    for (int j = 0; j < 2; ++j)
#pragma unroll
      for (int kk = 0; kk < 2; ++kk) {
        int r = wn * 32 + j * 16 + frow;
        br[j * 2 + kk] = *(const bf16x8*)(bB + r * 64 + ((g + kk * 4) ^ (r & 7)) * 8);
      }
    __builtin_amdgcn_s_setprio(1);
#pragma unroll
    for (int i = 0; i < 4; ++i)
#pragma unroll
      for (int j = 0; j < 2; ++j)
#pragma unroll
        for (int kk = 0; kk < 2; ++kk)
          acc[i][j] = __builtin_amdgcn_mfma_f32_16x16x32_bf16(
              ar[i * 2 + kk], br[j * 2 + kk], acc[i][j], 0, 0, 0);
    __builtin_amdgcn_s_setprio(0);
    __builtin_amdgcn_s_barrier();  // reads of buf[t] done before overwrite
  }
#undef STG

  int m0 = bm * 128 + wm * 64 + g * 4;
  int n0 = bn * 128 + wn * 32 + frow;
#pragma unroll
  for (int i = 0; i < 4; ++i) {
#pragma unroll
    for (int j = 0; j < 2; ++j) {
      int n = n0 + j * 16;
      float bv = (flags & 1) ? bias[n] : 0.f;
#pragma unroll
      for (int q = 0; q < 4; ++q) {
        int m = m0 + i * 16 + q;
        size_t off = (size_t)m * ldC + n;
        float v = acc[i][j][q] + bv;
        if (flags & 4) v = 0.5f * v * (1.0f + erff(v * 0.70710678118f));
        if (flags & 2) v += resid[off];
        if (flags & 8) ((u16*)Cout)[off] = f2b(v);
        else           ((float*)Cout)[off] = v;
      }
    }
  }
}

// ---- lm_head 256x256 GEMM, K=768 fixed, 8 waves, dbuf + 4-phase + fused LSE ----
__global__ __launch_bounds__(512, 2) void k_lm256(
    const u16* __restrict__ A,   // [4096][768] bf16
    const u16* __restrict__ B,   // [VCHUNK][768] bf16
    float* __restrict__ C,       // logits [4096][V]
    float* __restrict__ pm, float* __restrict__ ps,  // [4096][PBT]
    int gc0) {                   // global col offset of this chunk
  __shared__ __attribute__((aligned(16))) u16 lds[2][2][2][128 * 64];
  __shared__ float pml[256][4], psl[256][4];
  const int K = 768, NT = 12;
  int tid = threadIdx.x, w = tid >> 6, lane = tid & 63;
  int wm = w >> 2, wn = w & 3;
  int bm = blockIdx.y, bn = blockIdx.x;
  int frow = lane & 15, g = lane >> 4;
  int sr = lane >> 3, scu = lane & 7;
  const u16* Abase = A + (size_t)bm * 256 * K;
  const u16* Bbase = B + (size_t)bn * 256 * K;

  f32x4 acc[8][4];
#pragma unroll
  for (int i = 0; i < 8; ++i)
#pragma unroll
    for (int j = 0; j < 4; ++j) acc[i][j] = (f32x4)(0.f);

#define STAGE(t, h)                                                       \
  {                                                                       \
    const u16* src = ((h) < 2 ? Abase : Bbase) + (size_t)(((h)&1) * 128) * K; \
    u16* dst = &lds[(t) & 1][(h) >> 1][(h)&1][0];                         \
    _Pragma("unroll") for (int rr = 0; rr < 2; ++rr) {                    \
      int row = rr * 64 + w * 8 + sr;                                     \
      int gcu = scu ^ (row & 7);                                          \
      gll16(src + (size_t)row * K + (t) * 64 + gcu * 8,                   \
            dst + (rr * 64 + w * 8) * 64);                                \
    }                                                                     \
  }

  bf16x8 ar[8], br[8];
#define LDA(T_, ILO)                                                      \
  {                                                                       \
    const u16* base = &lds[(T_)&1][0][wm][0];                             \
    _Pragma("unroll") for (int ii = 0; ii < 4; ++ii)                      \
    _Pragma("unroll") for (int kk = 0; kk < 2; ++kk) {                    \
      int ri = ((ILO) + ii) * 16 + frow;                                  \
      int u = (g + kk * 4) ^ (ri & 7);                                    \
      ar[ii * 2 + kk] = *(const bf16x8*)(base + ri * 64 + u * 8);         \
    }                                                                     \
  }
#define LDB(T_, JLO, BO)                                                  \
  {                                                                       \
    const u16* base = &lds[(T_)&1][1][wn >> 1][0];                        \
    _Pragma("unroll") for (int jj = 0; jj < 2; ++jj)                      \
    _Pragma("unroll") for (int kk = 0; kk < 2; ++kk) {                    \
      int rj = (wn & 1) * 64 + ((JLO) + jj) * 16 + frow;                  \
      int u = (g + kk * 4) ^ (rj & 7);                                    \
      br[(BO) + jj * 2 + kk] = *(const bf16x8*)(base + rj * 64 + u * 8);  \
    }                                                                     \
  }
#define MFMA16(ILO, JLO, BO)                                              \
  _Pragma("unroll") for (int ii = 0; ii < 4; ++ii)                        \
  _Pragma("unroll") for (int jj = 0; jj < 2; ++jj)                        \
  _Pragma("unroll") for (int kk = 0; kk < 2; ++kk)                        \
    acc[(ILO) + ii][(JLO) + jj] = __builtin_amdgcn_mfma_f32_16x16x32_bf16( \
        ar[ii * 2 + kk], br[(BO) + jj * 2 + kk], acc[(ILO) + ii][(JLO) + jj], 0, 0, 0);

  STAGE(0, 0); STAGE(0, 1); STAGE(0, 2); STAGE(0, 3);
  asm volatile("s_waitcnt vmcnt(0)");
  __builtin_amdgcn_s_barrier();

  for (int t = 0; t < NT; ++t) {
    bool pf = (t + 1 < NT);
    LDA(t, 0); LDB(t, 0, 0);
    if (pf) STAGE(t + 1, 0);
    __builtin_amdgcn_s_setprio(1);
    MFMA16(0, 0, 0);
    __builtin_amdgcn_s_setprio(0);
    __builtin_amdgcn_s_barrier();
    LDB(t, 2, 4);
    if (pf) STAGE(t + 1, 1);
    __builtin_amdgcn_s_setprio(1);
    MFMA16(0, 2, 4);
    __builtin_amdgcn_s_setprio(0);
    __builtin_amdgcn_s_barrier();
    LDA(t, 4);
    if (pf) STAGE(t + 1, 2);
    __builtin_amdgcn_s_setprio(1);
    MFMA16(4, 2, 4);
    __builtin_amdgcn_s_setprio(0);
    __builtin_amdgcn_s_barrier();
    if (pf) STAGE(t + 1, 3);
    __builtin_amdgcn_s_setprio(1);
    MFMA16(4, 0, 0);
    __builtin_amdgcn_s_setprio(0);
    asm volatile("s_waitcnt vmcnt(0)");
    __builtin_amdgcn_s_barrier();
  }

#pragma unroll
  for (int ii = 0; ii < 8; ++ii) {
#pragma unroll
    for (int q = 0; q < 4; ++q) {
      float mx = fmaxf(fmaxf(acc[ii][0][q], acc[ii][1][q]),
                       fmaxf(acc[ii][2][q], acc[ii][3][q]));
      mx = fmaxf(mx, __shfl_xor(mx, 1, 64));
      mx = fmaxf(mx, __shfl_xor(mx, 2, 64));
      mx = fmaxf(mx, __shfl_xor(mx, 4, 64));
      mx = fmaxf(mx, __shfl_xor(mx, 8, 64));
      float sm = 0.f;
#pragma unroll
      for (int jj = 0; jj < 4; ++jj) sm += __expf(acc[ii][jj][q] - mx);
      sm += __shfl_xor(sm, 1, 64);
      sm += __shfl_xor(sm, 2, 64);
      sm += __shfl_xor(sm, 4, 64);
      sm += __shfl_xor(sm, 8, 64);
      int lrow = wm * 128 + ii * 16 + g * 4 + q;
      if (frow == 0) { pml[lrow][wn] = mx; psl[lrow][wn] = sm; }
      size_t off = (size_t)(bm * 256 + lrow) * V + gc0 + bn * 256 + wn * 64 + frow;
#pragma unroll
      for (int jj = 0; jj < 4; ++jj) C[off + jj * 16] = acc[ii][jj][q];
    }
  }
  __syncthreads();
  if (tid < 256) {
    float m = fmaxf(fmaxf(pml[tid][0], pml[tid][1]), fmaxf(pml[tid][2], pml[tid][3]));
    float s = 0.f;
#pragma unroll
    for (int w4 = 0; w4 < 4; ++w4) s += psl[tid][w4] * __expf(pml[tid][w4] - m);
    size_t grow = bm * 256 + tid;
    int pb = gc0 / 256 + bn;
    pm[grow * PBT + pb] = m;
    ps[grow * PBT + pb] = s;
  }
#undef STAGE
#undef LDA
#undef LDB
#undef MFMA16
}

// ---- MFMA flash attention: qkv bf16 [M,2304] -> y bf16 [M,768] ----
__global__ __launch_bounds__(256) void k_fattn(const u16* __restrict__ qkv,
                                               u16* __restrict__ y) {
  __shared__ __attribute__((aligned(16))) u16 lQ[128 * 64];
  __shared__ __attribute__((aligned(16))) u16 lK[64 * 64];
  __shared__ __attribute__((aligned(16))) u16 lVt[64 * 64];
  __shared__ __attribute__((aligned(16))) u16 lP[128 * 64];
  int tid = threadIdx.x;
  int w = tid >> 6, lane = tid & 63;
  int qtb = blockIdx.x;
  int bh = blockIdx.y, b = bh / H, h = bh - b * H;
  int q0 = qtb * 128;
  const u16* base = qkv + (size_t)b * T * D3 + h * DH;
  int srow = lane >> 3;
  int scu = lane & 7;
  int frow = lane & 15, g = lane >> 4;
  int w16 = w * 16;
  int qrow = g * 4;

#pragma unroll
  for (int c = 0; c < 4; ++c) {
    int row = c * 32 + w * 8 + srow;
    int gcu = scu ^ (row & 7);
    gll16(base + (size_t)(q0 + row) * D3 + gcu * 8, lQ + (c * 32 + w * 8) * 64);
  }

  float m_r[2][4], l_r[2][4];
  f32x4 o[2][4];
#pragma unroll
  for (int s = 0; s < 2; ++s)
#pragma unroll
    for (int i = 0; i < 4; ++i) {
      m_r[s][i] = -1e30f; l_r[s][i] = 0.f; o[s][i] = (f32x4)(0.f);
    }

  int ktmax = 2 * qtb + 1;
  for (int kt = 0; kt <= ktmax; ++kt) {
    __syncthreads();
    int k0 = kt * 64;
#pragma unroll
    for (int c = 0; c < 2; ++c) {
      int row = c * 32 + w * 8 + srow;
      int gcu = scu ^ (row & 7);
      gll16(base + D + (size_t)(k0 + row) * D3 + gcu * 8, lK + (c * 32 + w * 8) * 64);
    }
#pragma unroll
    for (int p = 0; p < 2; ++p) {
      int kk = p * 32 + w * 8 + srow;
      uint4 vv = *(const uint4*)(base + 2 * D + (size_t)(k0 + kk) * D3 + scu * 8);
      unsigned vals[4] = {vv.x, vv.y, vv.z, vv.w};
#pragma unroll
      for (int e = 0; e < 4; ++e) {
        lVt[swzi(scu * 8 + 2 * e, kk)]     = (u16)(vals[e] & 0xffff);
        lVt[swzi(scu * 8 + 2 * e + 1, kk)] = (u16)(vals[e] >> 16);
      }
    }
    __syncthreads();

#pragma unroll
    for (int s = 0; s < 2; ++s) {
      if (kt > 2 * qtb + s) continue;
      int qs = s * 64 + w16;
      int f7 = frow & 7;
      bf16x8 aq0 = *(const bf16x8*)(lQ + (qs + frow) * 64 + (g ^ f7) * 8);
      bf16x8 aq1 = *(const bf16x8*)(lQ + (qs + frow) * 64 + ((g + 4) ^ f7) * 8);
      f32x4 sv[4];
#pragma unroll
      for (int kn = 0; kn < 4; ++kn) {
        bf16x8 bk0 = *(const bf16x8*)(lK + (kn * 16 + frow) * 64 + (g ^ f7) * 8);
        bf16x8 bk1 = *(const bf16x8*)(lK + (kn * 16 + frow) * 64 + ((g + 4) ^ f7) * 8);
        sv[kn] = __builtin_amdgcn_mfma_f32_16x16x32_bf16(aq0, bk0, (f32x4)(0.f), 0, 0, 0);
        sv[kn] = __builtin_amdgcn_mfma_f32_16x16x32_bf16(aq1, bk1, sv[kn], 0, 0, 0);
      }
#pragma unroll
      for (int kn = 0; kn < 4; ++kn)
#pragma unroll
        for (int qi = 0; qi < 4; ++qi) {
          float v = sv[kn][qi] * SCALE;
          if (kt == 2 * qtb + s) {
            int qg = q0 + qs + qrow + qi;
            int kg = k0 + kn * 16 + frow;
            if (kg > qg) v = -1e30f;
          }
          sv[kn][qi] = v;
        }
#pragma unroll
      for (int qi = 0; qi < 4; ++qi) {
        float rm = fmaxf(fmaxf(sv[0][qi], sv[1][qi]), fmaxf(sv[2][qi], sv[3][qi]));
        rm = fmaxf(rm, __shfl_xor(rm, 1, 64));
        rm = fmaxf(rm, __shfl_xor(rm, 2, 64));
        rm = fmaxf(rm, __shfl_xor(rm, 4, 64));
        rm = fmaxf(rm, __shfl_xor(rm, 8, 64));
        float mn = fmaxf(m_r[s][qi], rm);
        float alpha = __expf(m_r[s][qi] - mn);
        m_r[s][qi] = mn;
        float rs = 0.f;
#pragma unroll
        for (int kn = 0; kn < 4; ++kn) {
          float p = __expf(sv[kn][qi] - mn);
          sv[kn][qi] = p;
          rs += p;
        }
        rs += __shfl_xor(rs, 1, 64);
        rs += __shfl_xor(rs, 2, 64);
        rs += __shfl_xor(rs, 4, 64);
        rs += __shfl_xor(rs, 8, 64);
        l_r[s][qi] = l_r[s][qi] * alpha + rs;
#pragma unroll
        for (int df = 0; df < 4; ++df) o[s][df][qi] *= alpha;
      }
#pragma unroll
      for (int kn = 0; kn < 4; ++kn)
#pragma unroll
        for (int qi = 0; qi < 4; ++qi)
          lP[swzi(qs + qrow + qi, kn * 16 + frow)] = f2b(sv[kn][qi]);
      bf16x8 pa0 = *(const bf16x8*)(lP + swzi(qs + frow, g * 8));
      bf16x8 pa1 = *(const bf16x8*)(lP + swzi(qs + frow, 32 + g * 8));
#pragma unroll
      for (int df = 0; df < 4; ++df) {
        bf16x8 bv0 = *(const bf16x8*)(lVt + swzi(df * 16 + frow, g * 8));
        bf16x8 bv1 = *(const bf16x8*)(lVt + swzi(df * 16 + frow, 32 + g * 8));
        o[s][df] = __builtin_amdgcn_mfma_f32_16x16x32_bf16(pa0, bv0, o[s][df], 0, 0, 0);
        o[s][df] = __builtin_amdgcn_mfma_f32_16x16x32_bf16(pa1, bv1, o[s][df], 0, 0, 0);
      }
    }
  }

#pragma unroll
  for (int s = 0; s < 2; ++s)
#pragma unroll
    for (int df = 0; df < 4; ++df)
#pragma unroll
      for (int qi = 0; qi < 4; ++qi) {
        int qg = q0 + s * 64 + w16 + qrow + qi;
        y[(size_t)(b * T + qg) * D + h * DH + df * 16 + frow] =
            f2b(o[s][df][qi] / l_r[s][qi]);
      }
}

// ---- final LSE + NLL from partials; one wave per row ----
__global__ __launch_bounds__(256) void k_loss_rows(
    const float* __restrict__ pm, const float* __restrict__ ps,
    const float* __restrict__ logits, const int* __restrict__ targets,
    float* __restrict__ nll) {
  int lane = threadIdx.x & 63, wid = threadIdx.x >> 6;
  int row = blockIdx.x * 4 + wid;
  const float* pmr = pm + (size_t)row * PBT;
  const float* psr = ps + (size_t)row * PBT;
  float m = -1e30f;
  for (int i = lane; i < PBT; i += 64) m = fmaxf(m, pmr[i]);
#pragma unroll
  for (int off = 32; off; off >>= 1) m = fmaxf(m, __shfl_xor(m, off, 64));
  float s = 0.f;
  for (int i = lane; i < PBT; i += 64) s += psr[i] * __expf(pmr[i] - m);
#pragma unroll
  for (int off = 32; off; off >>= 1) s += __shfl_xor(s, off, 64);
  if (lane == 0) {
    int tgt = targets[row];
    nll[row] = (tgt != -100) ? (m + logf(s) - logits[(size_t)row * V + tgt]) : 0.f;
  }
}

__global__ __launch_bounds__(256) void k_loss_final(const float* __restrict__ nll,
                                                    const int* __restrict__ targets,
                                                    float* __restrict__ out) {
  __shared__ float buf4[4];
  float s = 0.f, c = 0.f;
  for (int i = threadIdx.x; i < M; i += 256) {
    s += nll[i];
    c += (targets[i] != -100) ? 1.f : 0.f;
  }
  s = block_reduce(s, false, buf4);
  c = block_reduce(c, false, buf4);
  if (threadIdx.x == 0) out[0] = s / fmaxf(c, 1.f);
}

extern "C" void kernel_launch(void* const* d_in, const int* in_sizes, int n_in,
                              void* d_out, int out_size, void* d_ws, size_t ws_size,
                              hipStream_t stream) {
  const int* idx       = (const int*)d_in[0];
  const int* targets   = (const int*)d_in[1];
  const float* tok     = (const float*)d_in[2];
  const float* pos     = (const float*)d_in[3];
  const float* qkv_w   = (const float*)d_in[4];
  const float* qkv_b   = (const float*)d_in[5];
  const float* proj_w  = (const float*)d_in[6];
  const float* proj_b  = (const float*)d_in[7];
  const float* fc1_w   = (const float*)d_in[8];
  const float* fc1_b   = (const float*)d_in[9];
  const float* fc2_w   = (const float*)d_in[10];
  const float* fc2_b   = (const float*)d_in[11];
  const float* ln1_w   = (const float*)d_in[12];
  const float* ln1_b   = (const float*)d_in[13];
  const float* ln2_w   = (const float*)d_in[14];
  const float* ln2_b   = (const float*)d_in[15];
  const float* lnf_w   = (const float*)d_in[16];
  const float* lnf_b   = (const float*)d_in[17];

  float* logits = (float*)d_out;

  // ---- ws layout (~39.1 MB) ----
  char* ws = (char*)d_ws;
  float* x   = (float*)ws;                  // M*D f32        12.58 MB
  u16* hb    = (u16*)(ws + 12582912);       // M*D bf16        6.29 MB
  u16* yb    = (u16*)(ws + 18874368);       // M*D bf16        6.29 MB
  u16* wb    = (u16*)(ws + 25165824);       // VCHUNK*D bf16   9.83 MB
  float* pm  = (float*)(ws + 34996224);     // M*PBT f32       2.05 MB
  float* ps  = (float*)(ws + 37044224);     // M*PBT f32       2.05 MB
  float* nll = (float*)(ws + 39092224);     // M f32           16 KB

  // ---- d_out scratch (dead before logits are written) ----
  u16* qkvb   = (u16*)logits;                        // M*D3 bf16
  u16* f1b    = (u16*)(logits + 9437184);            // M*F bf16
  u16* wqkv   = (u16*)(logits + 15728640);
  u16* wproj  = (u16*)(logits + 22806528);
  u16* wfc1   = (u16*)(logits + 25165824);
  u16* wfc2   = (u16*)(logits + 34603008);

  k_cvt<<<(L * D3 * D / 4 + 255) / 256, 256, 0, stream>>>(qkv_w, wqkv, L * D3 * D / 4);
  k_cvt<<<(L * D * D / 4 + 255) / 256, 256, 0, stream>>>(proj_w, wproj, L * D * D / 4);
  k_cvt<<<(L * F * D / 4 + 255) / 256, 256, 0, stream>>>(fc1_w, wfc1, L * F * D / 4);
  k_cvt<<<(L * D * F / 4 + 255) / 256, 256, 0, stream>>>(fc2_w, wfc2, L * D * F / 4);

  k_embed<<<(M * D) / 256, 256, 0, stream>>>(idx, tok, pos, x);

  for (int l = 0; l < L; ++l) {
    k_lnorm<<<M / 4, 256, 0, stream>>>(x, ln1_w + (size_t)l * D, ln1_b + (size_t)l * D, hb);
    k_gemm8<<<dim3(D3 / 128, M / 128), 512, 0, stream>>>(
        hb, wqkv + (size_t)l * D3 * D, qkv_b + (size_t)l * D3, nullptr, qkvb, D, D3, 9);
    k_fattn<<<dim3(T / 128, BATCH * H), 256, 0, stream>>>(qkvb, yb);
    k_gemm8<<<dim3(D / 128, M / 128), 512, 0, stream>>>(
        yb, wproj + (size_t)l * D * D, proj_b + (size_t)l * D, x, x, D, D, 3);
    k_lnorm<<<M / 4, 256, 0, stream>>>(x, ln2_w + (size_t)l * D, ln2_b + (size_t)l * D, hb);
    k_gemm8<<<dim3(F / 128, M / 128), 512, 0, stream>>>(
        hb, wfc1 + (size_t)l * F * D, fc1_b + (size_t)l * F, nullptr, f1b, D, F, 13);
    k_gemm8<<<dim3(D / 128, M / 128), 512, 0, stream>>>(
        f1b, wfc2 + (size_t)l * D * F, fc2_b + (size_t)l * D, x, x, F, D, 3);
  }

  k_lnorm<<<M / 4, 256, 0, stream>>>(x, lnf_w, lnf_b, hb);
  for (int c = 0; c < 5; ++c) {
    k_cvt<<<(VCHUNK * D / 4 + 255) / 256, 256, 0, stream>>>(
        tok + (size_t)c * VCHUNK * D, wb, VCHUNK * D / 4);
    k_lm256<<<dim3(VCHUNK / 256, M / 256), 512, 0, stream>>>(
        hb, wb, logits, pm, ps, c * VCHUNK);
  }
  k_loss_rows<<<M / 4, 256, 0, stream>>>(pm, ps, logits, targets, nll);
  k_loss_final<<<1, 256, 0, stream>>>(nll, targets, logits + (size_t)M * V);
}